// Round 1
// baseline (1767.080 us; speedup 1.0000x reference)
//
#include <hip/hip_runtime.h>
#include <cstddef>

#define DIM 128
#define DH 64
#define NC 40

// -------------------- scatter-add aggregation --------------------
// One wave per edge: 64 lanes cover the 128 feature dims (2 each).
__global__ __launch_bounds__(256) void k_scatter(
    const float* __restrict__ feat,
    const int* __restrict__ srcv,
    const int* __restrict__ dstv,
    const float* __restrict__ wv,
    float* __restrict__ agg,
    float* __restrict__ deg,
    int E, int do_deg)
{
    int lane = threadIdx.x & 63;
    int wid  = (int)((blockIdx.x * blockDim.x + threadIdx.x) >> 6);
    int nw   = (int)((gridDim.x * blockDim.x) >> 6);
    for (int e = wid; e < E; e += nw) {
        int s   = srcv[e];
        int d   = dstv[e];
        float w = wv[e];
        const float* f = feat + (size_t)s * DIM;
        float* a       = agg  + (size_t)d * DIM;
        atomicAdd(&a[lane],      w * f[lane]);
        atomicAdd(&a[lane + 64], w * f[lane + 64]);
        if (do_deg && lane == 0) atomicAdd(&deg[d], w);
    }
}

#define SWS 132   // sA row stride (floats): 132%32=4 -> r-groups hit distinct banks, float4 aligned
#define SWH 68    // sW row stride: 68 -> (4*j0+k)%32, 16 j-lanes -> 2 lanes/bank (free)

// hidden = relu((agg/deg) @ W1^T + b1), 16 rows per block, W1 staged in 2 K-halves
__global__ __launch_bounds__(256) void k_dense1(
    const float* __restrict__ agg,
    const float* __restrict__ deg,
    const float* __restrict__ W1,
    const float* __restrict__ b1,
    float* __restrict__ hidden,
    int n)
{
    __shared__ float sW[DIM * SWH];   // 34816 B
    __shared__ float sA[16 * SWS];    // 8448 B
    int t = threadIdx.x;
    int row0 = (int)blockIdx.x * 16;

    // load 16 scaled rows
    for (int i = t; i < 16 * DIM; i += 256) {
        int r = i >> 7, k = i & (DIM - 1);
        int row = row0 + r;
        float v = 0.f;
        if (row < n) {
            float dg = deg[row];
            dg = dg > 1.f ? dg : 1.f;
            v = agg[(size_t)row * DIM + k] / dg;
        }
        sA[r * SWS + k] = v;
    }

    int r  = t >> 4;   // 0..15 row
    int j0 = t & 15;   // cols j0 + 16*jj
    float acc[8];
    #pragma unroll
    for (int jj = 0; jj < 8; ++jj) acc[jj] = b1[j0 + 16 * jj];

    for (int kh = 0; kh < 2; ++kh) {
        __syncthreads();   // sA visible (kh=0); prev compute done before overwrite (kh=1)
        for (int i = t; i < DIM * 64; i += 256) {
            int j = i >> 6, k = i & 63;
            sW[j * SWH + k] = W1[j * DIM + kh * 64 + k];
        }
        __syncthreads();
        #pragma unroll 4
        for (int k = 0; k < 64; k += 4) {
            float4 a4 = *(const float4*)&sA[r * SWS + kh * 64 + k];
            #pragma unroll
            for (int jj = 0; jj < 8; ++jj) {
                float4 w4 = *(const float4*)&sW[(j0 + 16 * jj) * SWH + k];
                acc[jj] += a4.x * w4.x + a4.y * w4.y + a4.z * w4.z + a4.w * w4.w;
            }
        }
    }

    int row = row0 + r;
    if (row >= n) return;
    float* h = hidden + (size_t)row * DIM;
    #pragma unroll
    for (int jj = 0; jj < 8; ++jj) {
        float v = acc[jj];
        h[j0 + 16 * jj] = v > 0.f ? v : 0.f;
    }
}

#define SW3 68

// embedding = (agg/deg) @ W2^T + b2 ; logits = embedding @ W3^T + b3
__global__ __launch_bounds__(256) void k_dense2(
    const float* __restrict__ agg,
    const float* __restrict__ deg,
    const float* __restrict__ W2,
    const float* __restrict__ b2,
    const float* __restrict__ W3,
    const float* __restrict__ b3,
    float* __restrict__ out_emb,
    float* __restrict__ out_log,
    int n)
{
    __shared__ float sW2[DH * SWS];   // 33792 B
    __shared__ float sW3[NC * SW3];   // 10880 B
    __shared__ float sA[16 * SWS];    //  8448 B
    __shared__ float sE[16 * SW3];    //  4352 B
    int t = threadIdx.x;
    int row0 = (int)blockIdx.x * 16;

    for (int i = t; i < DH * DIM; i += 256) {
        int j = i >> 7, k = i & (DIM - 1);
        sW2[j * SWS + k] = W2[i];
    }
    for (int i = t; i < NC * DH; i += 256) {
        int c = i / DH, k = i % DH;
        sW3[c * SW3 + k] = W3[i];
    }
    for (int i = t; i < 16 * DIM; i += 256) {
        int r = i >> 7, k = i & (DIM - 1);
        int row = row0 + r;
        float v = 0.f;
        if (row < n) {
            float dg = deg[row];
            dg = dg > 1.f ? dg : 1.f;
            v = agg[(size_t)row * DIM + k] / dg;
        }
        sA[r * SWS + k] = v;
    }
    __syncthreads();

    {
        int r  = t >> 4;
        int j0 = t & 15;
        int row = row0 + r;
        float acc[4];
        #pragma unroll
        for (int jj = 0; jj < 4; ++jj) acc[jj] = b2[j0 + 16 * jj];
        #pragma unroll 4
        for (int k = 0; k < DIM; k += 4) {
            float4 a4 = *(const float4*)&sA[r * SWS + k];
            #pragma unroll
            for (int jj = 0; jj < 4; ++jj) {
                float4 w4 = *(const float4*)&sW2[(j0 + 16 * jj) * SWS + k];
                acc[jj] += a4.x * w4.x + a4.y * w4.y + a4.z * w4.z + a4.w * w4.w;
            }
        }
        #pragma unroll
        for (int jj = 0; jj < 4; ++jj) {
            sE[r * SW3 + j0 + 16 * jj] = acc[jj];
            if (row < n) out_emb[(size_t)row * DH + j0 + 16 * jj] = acc[jj];
        }
    }
    __syncthreads();

    for (int idx = t; idx < 16 * NC; idx += 256) {
        int r = idx / NC, c = idx % NC;
        int row = row0 + r;
        if (row >= n) continue;
        float acc = b3[c];
        #pragma unroll 8
        for (int k = 0; k < DH; ++k)
            acc += sE[r * SW3 + k] * sW3[c * SW3 + k];
        out_log[(size_t)row * NC + c] = acc;
    }
}

extern "C" void kernel_launch(void* const* d_in, const int* in_sizes, int n_in,
                              void* d_out, int out_size, void* d_ws, size_t ws_size,
                              hipStream_t stream)
{
    const float* feat = (const float*)d_in[0];
    const int*   eidx = (const int*)d_in[1];
    const float* ew   = (const float*)d_in[2];
    const float* W1   = (const float*)d_in[3];
    const float* b1   = (const float*)d_in[4];
    const float* W2   = (const float*)d_in[5];
    const float* b2   = (const float*)d_in[6];
    const float* W3   = (const float*)d_in[7];
    const float* b3   = (const float*)d_in[8];

    int E = in_sizes[2];            // edge_weight count
    int n = in_sizes[0] / DIM;      // 100000 nodes

    const int* srcv = eidx;         // edge_index[0]
    const int* dstv = eidx + E;     // edge_index[1]

    float* agg    = (float*)d_ws;                  // n*128 f32
    float* hidden = agg + (size_t)n * DIM;         // n*128 f32
    float* deg    = hidden + (size_t)n * DIM;      // n f32

    float* out_emb = (float*)d_out;
    float* out_log = out_emb + (size_t)n * DH;

    hipMemsetAsync(agg, 0, (size_t)n * DIM * sizeof(float), stream);
    hipMemsetAsync(deg, 0, (size_t)n * sizeof(float), stream);

    k_scatter<<<4096, 256, 0, stream>>>(feat, srcv, dstv, ew, agg, deg, E, 1);

    int nblk = (n + 15) / 16;
    k_dense1<<<nblk, 256, 0, stream>>>(agg, deg, W1, b1, hidden, n);

    hipMemsetAsync(agg, 0, (size_t)n * DIM * sizeof(float), stream);

    k_scatter<<<4096, 256, 0, stream>>>(hidden, srcv, dstv, ew, agg, nullptr, E, 0);

    k_dense2<<<nblk, 256, 0, stream>>>(agg, deg, W2, b2, W3, b3, out_emb, out_log, n);
}

// Round 2
// 891.328 us; speedup vs baseline: 1.9825x; 1.9825x over previous
//
#include <hip/hip_runtime.h>
#include <cstddef>

#define DIM 128
#define DH 64
#define NC 40
#define SCHUNK 1024

// ==================== CSR build ====================

__global__ __launch_bounds__(256) void k_hist(
    const int* __restrict__ dstv, const float* __restrict__ wv,
    int* __restrict__ cnt /* = row_start+1 */, float* __restrict__ deg, int E)
{
    int i = blockIdx.x * blockDim.x + threadIdx.x;
    int stride = gridDim.x * blockDim.x;
    for (int e = i; e < E; e += stride) {
        int d = dstv[e];
        atomicAdd(&cnt[d], 1);
        atomicAdd(&deg[d], wv[e]);
    }
}

__global__ __launch_bounds__(256) void k_scan1(
    const int* __restrict__ a, int* __restrict__ bsum, int m)
{
    __shared__ int sd[256];
    int t = threadIdx.x;
    int base = blockIdx.x * SCHUNK + t * 4;
    int s = 0;
    #pragma unroll
    for (int i = 0; i < 4; ++i) { int idx = base + i; if (idx < m) s += a[idx]; }
    sd[t] = s; __syncthreads();
    for (int off = 128; off > 0; off >>= 1) {
        if (t < off) sd[t] += sd[t + off];
        __syncthreads();
    }
    if (t == 0) bsum[blockIdx.x] = sd[0];
}

__global__ __launch_bounds__(256) void k_scan2(int* __restrict__ bsum, int B)
{
    __shared__ int sd[256];
    int t = threadIdx.x;
    int v = (t < B) ? bsum[t] : 0;
    sd[t] = v; __syncthreads();
    for (int off = 1; off < 256; off <<= 1) {
        int x = (t >= off) ? sd[t - off] : 0;
        __syncthreads();
        sd[t] += x;
        __syncthreads();
    }
    if (t < B) bsum[t] = sd[t] - v;   // exclusive
}

__global__ __launch_bounds__(256) void k_scan3(
    int* __restrict__ a, const int* __restrict__ bsum, int m)
{
    __shared__ int sth[256];
    int t = threadIdx.x;
    int base = blockIdx.x * SCHUNK + t * 4;
    int v[4]; int s = 0;
    #pragma unroll
    for (int i = 0; i < 4; ++i) { int idx = base + i; v[i] = (idx < m) ? a[idx] : 0; s += v[i]; }
    sth[t] = s; __syncthreads();
    int own = s;
    for (int off = 1; off < 256; off <<= 1) {
        int x = (t >= off) ? sth[t - off] : 0;
        __syncthreads();
        sth[t] += x;
        __syncthreads();
    }
    int run = sth[t] - own + bsum[blockIdx.x];
    #pragma unroll
    for (int i = 0; i < 4; ++i) {
        run += v[i];
        int idx = base + i;
        if (idx < m) a[idx] = run;     // inclusive scan overall
    }
}

__global__ __launch_bounds__(256) void k_fill(
    const int* __restrict__ srcv, const int* __restrict__ dstv,
    const float* __restrict__ wv, int* __restrict__ fill_pos,
    int2* __restrict__ csr, int E)
{
    int i = blockIdx.x * blockDim.x + threadIdx.x;
    int stride = gridDim.x * blockDim.x;
    for (int e = i; e < E; e += stride) {
        int d = dstv[e];
        int pos = atomicAdd(&fill_pos[d], 1);
        csr[pos] = make_int2(srcv[e], __float_as_int(wv[e]));
    }
}

// ==================== CSR gather (normalized) ====================
// One wave per node: 64 lanes cover 128 dims as float2; edges broadcast via shfl.
__global__ __launch_bounds__(256) void k_gather(
    const float* __restrict__ feat, const int* __restrict__ row_start,
    const int2* __restrict__ csr, const float* __restrict__ deg,
    float* __restrict__ out, int n)
{
    int lane = threadIdx.x & 63;
    int wid  = (int)((blockIdx.x * blockDim.x + threadIdx.x) >> 6);
    int nw   = (int)((gridDim.x * blockDim.x) >> 6);
    for (int v = wid; v < n; v += nw) {
        int beg = row_start[v], end = row_start[v + 1];
        float2 acc = make_float2(0.f, 0.f);
        for (int b = beg; b < end; b += 64) {
            int cnt = end - b; if (cnt > 64) cnt = 64;
            int2 ew = make_int2(0, 0);
            if (lane < cnt) ew = csr[b + lane];
            int sv = ew.x; float wl = __int_as_float(ew.y);
            for (int j = 0; j < cnt; ++j) {
                int   s = __shfl(sv, j);
                float w = __shfl(wl, j);
                float2 f = ((const float2*)(feat + (size_t)s * DIM))[lane];
                acc.x += w * f.x;
                acc.y += w * f.y;
            }
        }
        float dg = deg[v]; dg = dg > 1.f ? dg : 1.f;
        float inv = 1.f / dg;
        ((float2*)(out + (size_t)v * DIM))[lane] = make_float2(acc.x * inv, acc.y * inv);
    }
}

// ==================== fallback atomic scatter ====================
__global__ __launch_bounds__(256) void k_scatter(
    const float* __restrict__ feat,
    const int* __restrict__ srcv, const int* __restrict__ dstv,
    const float* __restrict__ wv,
    float* __restrict__ agg, float* __restrict__ deg, int E, int do_deg)
{
    int lane = threadIdx.x & 63;
    int wid  = (int)((blockIdx.x * blockDim.x + threadIdx.x) >> 6);
    int nw   = (int)((gridDim.x * blockDim.x) >> 6);
    for (int e = wid; e < E; e += nw) {
        int s = srcv[e], d = dstv[e];
        float w = wv[e];
        const float* f = feat + (size_t)s * DIM;
        float* a = agg + (size_t)d * DIM;
        atomicAdd(&a[lane],      w * f[lane]);
        atomicAdd(&a[lane + 64], w * f[lane + 64]);
        if (do_deg && lane == 0) atomicAdd(&deg[d], w);
    }
}

// ==================== dense layers ====================
#define SWS 132
#define SWH 68
#define SW3 68

// hidden = relu(in @ W1^T + b1); if deg!=nullptr, in rows divided by clamp(deg,1)
__global__ __launch_bounds__(256) void k_dense1(
    const float* __restrict__ in, const float* __restrict__ deg,
    const float* __restrict__ W1, const float* __restrict__ b1,
    float* __restrict__ hidden, int n)
{
    __shared__ float sW[DIM * SWH];
    __shared__ float sA[16 * SWS];
    int t = threadIdx.x;
    int row0 = (int)blockIdx.x * 16;

    for (int i = t; i < 16 * DIM; i += 256) {
        int r = i >> 7, k = i & (DIM - 1);
        int row = row0 + r;
        float v = 0.f;
        if (row < n) {
            v = in[(size_t)row * DIM + k];
            if (deg) {
                float dg = deg[row]; dg = dg > 1.f ? dg : 1.f;
                v /= dg;
            }
        }
        sA[r * SWS + k] = v;
    }

    int r  = t >> 4;
    int j0 = t & 15;
    float acc[8];
    #pragma unroll
    for (int jj = 0; jj < 8; ++jj) acc[jj] = b1[j0 + 16 * jj];

    for (int kh = 0; kh < 2; ++kh) {
        __syncthreads();
        for (int i = t; i < DIM * 64; i += 256) {
            int j = i >> 6, k = i & 63;
            sW[j * SWH + k] = W1[j * DIM + kh * 64 + k];
        }
        __syncthreads();
        #pragma unroll 4
        for (int k = 0; k < 64; k += 4) {
            float4 a4 = *(const float4*)&sA[r * SWS + kh * 64 + k];
            #pragma unroll
            for (int jj = 0; jj < 8; ++jj) {
                float4 w4 = *(const float4*)&sW[(j0 + 16 * jj) * SWH + k];
                acc[jj] += a4.x * w4.x + a4.y * w4.y + a4.z * w4.z + a4.w * w4.w;
            }
        }
    }

    int row = row0 + r;
    if (row >= n) return;
    float* h = hidden + (size_t)row * DIM;
    #pragma unroll
    for (int jj = 0; jj < 8; ++jj) {
        float v = acc[jj];
        h[j0 + 16 * jj] = v > 0.f ? v : 0.f;
    }
}

__global__ __launch_bounds__(256) void k_dense2(
    const float* __restrict__ in, const float* __restrict__ deg,
    const float* __restrict__ W2, const float* __restrict__ b2,
    const float* __restrict__ W3, const float* __restrict__ b3,
    float* __restrict__ out_emb, float* __restrict__ out_log, int n)
{
    __shared__ float sW2[DH * SWS];
    __shared__ float sW3[NC * SW3];
    __shared__ float sA[16 * SWS];
    __shared__ float sE[16 * SW3];
    int t = threadIdx.x;
    int row0 = (int)blockIdx.x * 16;

    for (int i = t; i < DH * DIM; i += 256) {
        int j = i >> 7, k = i & (DIM - 1);
        sW2[j * SWS + k] = W2[i];
    }
    for (int i = t; i < NC * DH; i += 256) {
        int c = i / DH, k = i % DH;
        sW3[c * SW3 + k] = W3[i];
    }
    for (int i = t; i < 16 * DIM; i += 256) {
        int r = i >> 7, k = i & (DIM - 1);
        int row = row0 + r;
        float v = 0.f;
        if (row < n) {
            v = in[(size_t)row * DIM + k];
            if (deg) {
                float dg = deg[row]; dg = dg > 1.f ? dg : 1.f;
                v /= dg;
            }
        }
        sA[r * SWS + k] = v;
    }
    __syncthreads();

    {
        int r  = t >> 4;
        int j0 = t & 15;
        int row = row0 + r;
        float acc[4];
        #pragma unroll
        for (int jj = 0; jj < 4; ++jj) acc[jj] = b2[j0 + 16 * jj];
        #pragma unroll 4
        for (int k = 0; k < DIM; k += 4) {
            float4 a4 = *(const float4*)&sA[r * SWS + k];
            #pragma unroll
            for (int jj = 0; jj < 4; ++jj) {
                float4 w4 = *(const float4*)&sW2[(j0 + 16 * jj) * SWS + k];
                acc[jj] += a4.x * w4.x + a4.y * w4.y + a4.z * w4.z + a4.w * w4.w;
            }
        }
        #pragma unroll
        for (int jj = 0; jj < 4; ++jj) {
            sE[r * SW3 + j0 + 16 * jj] = acc[jj];
            if (row < n) out_emb[(size_t)row * DH + j0 + 16 * jj] = acc[jj];
        }
    }
    __syncthreads();

    for (int idx = t; idx < 16 * NC; idx += 256) {
        int r = idx / NC, c = idx % NC;
        int row = row0 + r;
        if (row >= n) continue;
        float acc = b3[c];
        #pragma unroll 8
        for (int k = 0; k < DH; ++k)
            acc += sE[r * SW3 + k] * sW3[c * SW3 + k];
        out_log[(size_t)row * NC + c] = acc;
    }
}

// ==================== launch ====================
extern "C" void kernel_launch(void* const* d_in, const int* in_sizes, int n_in,
                              void* d_out, int out_size, void* d_ws, size_t ws_size,
                              hipStream_t stream)
{
    const float* feat = (const float*)d_in[0];
    const int*   eidx = (const int*)d_in[1];
    const float* ew   = (const float*)d_in[2];
    const float* W1   = (const float*)d_in[3];
    const float* b1   = (const float*)d_in[4];
    const float* W2   = (const float*)d_in[5];
    const float* b2   = (const float*)d_in[6];
    const float* W3   = (const float*)d_in[7];
    const float* b3   = (const float*)d_in[8];

    int E = in_sizes[2];
    int n = in_sizes[0] / DIM;

    const int* srcv = eidx;
    const int* dstv = eidx + E;

    float* out_emb = (float*)d_out;
    float* out_log = out_emb + (size_t)n * DH;

    size_t nf = (size_t)n * DIM;
    float* aggn   = (float*)d_ws;         // nf
    float* hidden = aggn + nf;            // nf
    float* deg    = hidden + nf;          // n
    int*   row_start = (int*)(deg + n);   // n+1
    int*   fill_pos  = row_start + (n + 1); // n
    size_t ofs = 2 * nf + (size_t)n + (size_t)(n + 1) + (size_t)n;
    ofs = (ofs + 1) & ~(size_t)1;         // 8B-align for int2
    int2*  csr = (int2*)((float*)d_ws + ofs); // E int2
    size_t need = (ofs + 2 * (size_t)E) * sizeof(float);

    int nblk = (n + 15) / 16;

    if (need <= ws_size) {
        // -------- CSR gather path --------
        hipMemsetAsync(row_start, 0, (size_t)(n + 1) * sizeof(int), stream);
        hipMemsetAsync(deg, 0, (size_t)n * sizeof(float), stream);

        k_hist<<<2048, 256, 0, stream>>>(dstv, ew, row_start + 1, deg, E);

        int m = n + 1;
        int B = (m + SCHUNK - 1) / SCHUNK;
        k_scan1<<<B, 256, 0, stream>>>(row_start, fill_pos /*temp bsum? no*/, m);
        // NOTE: need a separate small bsum buffer; reuse tail of fill_pos is unsafe
        // since fill_pos must hold n ints later — but scan phases finish before fill.
        // fill_pos is free until the memcpy below, so using its first B ints is fine.
        k_scan2<<<1, 256, 0, stream>>>(fill_pos, B);
        k_scan3<<<B, 256, 0, stream>>>(row_start, fill_pos, m);

        hipMemcpyAsync(fill_pos, row_start, (size_t)n * sizeof(int),
                       hipMemcpyDeviceToDevice, stream);
        k_fill<<<2048, 256, 0, stream>>>(srcv, dstv, ew, fill_pos, csr, E);

        int gblk = (n + 3) / 4;   // 4 waves/block, 1 wave/node
        k_gather<<<gblk, 256, 0, stream>>>(feat, row_start, csr, deg, aggn, n);
        k_dense1<<<nblk, 256, 0, stream>>>(aggn, nullptr, W1, b1, hidden, n);
        k_gather<<<gblk, 256, 0, stream>>>(hidden, row_start, csr, deg, aggn, n);
        k_dense2<<<nblk, 256, 0, stream>>>(aggn, nullptr, W2, b2, W3, b3, out_emb, out_log, n);
    } else {
        // -------- fallback: atomic scatter path --------
        hipMemsetAsync(aggn, 0, nf * sizeof(float), stream);
        hipMemsetAsync(deg, 0, (size_t)n * sizeof(float), stream);
        k_scatter<<<4096, 256, 0, stream>>>(feat, srcv, dstv, ew, aggn, deg, E, 1);
        k_dense1<<<nblk, 256, 0, stream>>>(aggn, deg, W1, b1, hidden, n);
        hipMemsetAsync(aggn, 0, nf * sizeof(float), stream);
        k_scatter<<<4096, 256, 0, stream>>>(hidden, srcv, dstv, ew, aggn, nullptr, E, 0);
        k_dense2<<<nblk, 256, 0, stream>>>(aggn, deg, W2, b2, W3, b3, out_emb, out_log, n);
    }
}

// Round 3
// 727.774 us; speedup vs baseline: 2.4281x; 1.2247x over previous
//
#include <hip/hip_runtime.h>
#include <cstddef>

#define DIM 128
#define DH 64
#define NC 40
#define SCHUNK 1024
#define DEG_SHIFT 41
#define DEG_SCALE 1048576.0f   // 2^20 fixed-point for deg

typedef unsigned long long u64;

// ==================== CSR build ====================
// One 64-bit atomic per edge: count in bits [61:41], fixed-point deg in [40:0].
// Returned old value gives the edge's rank within its dst bucket.
__global__ __launch_bounds__(256) void k_hist_rank(
    const int* __restrict__ dstv, const float* __restrict__ wv,
    u64* __restrict__ packed, int* __restrict__ rank, int E)
{
    int e = blockIdx.x * blockDim.x + threadIdx.x;
    int stride = gridDim.x * blockDim.x;
    for (; e < E; e += stride) {
        int d = dstv[e];
        unsigned int wfx = (unsigned int)(wv[e] * DEG_SCALE + 0.5f);
        u64 old = atomicAdd(&packed[d], (1ULL << DEG_SHIFT) | (u64)wfx);
        rank[e] = (int)(old >> DEG_SHIFT);
    }
}

// counts -> row_start[v+1] (pre-scan), deg float
__global__ __launch_bounds__(256) void k_extract(
    const u64* __restrict__ packed, int* __restrict__ row_start,
    float* __restrict__ deg, int n)
{
    int v = blockIdx.x * blockDim.x + threadIdx.x;
    if (v >= n) return;
    u64 p = packed[v];
    row_start[v + 1] = (int)(p >> DEG_SHIFT);
    deg[v] = (float)(p & ((1ULL << DEG_SHIFT) - 1)) * (1.0f / DEG_SCALE);
}

__global__ __launch_bounds__(256) void k_scan1(
    const int* __restrict__ a, int* __restrict__ bsum, int m)
{
    __shared__ int sd[256];
    int t = threadIdx.x;
    int base = blockIdx.x * SCHUNK + t * 4;
    int s = 0;
    #pragma unroll
    for (int i = 0; i < 4; ++i) { int idx = base + i; if (idx < m) s += a[idx]; }
    sd[t] = s; __syncthreads();
    for (int off = 128; off > 0; off >>= 1) {
        if (t < off) sd[t] += sd[t + off];
        __syncthreads();
    }
    if (t == 0) bsum[blockIdx.x] = sd[0];
}

__global__ __launch_bounds__(256) void k_scan2(int* __restrict__ bsum, int B)
{
    __shared__ int sd[256];
    int t = threadIdx.x;
    int v = (t < B) ? bsum[t] : 0;
    sd[t] = v; __syncthreads();
    for (int off = 1; off < 256; off <<= 1) {
        int x = (t >= off) ? sd[t - off] : 0;
        __syncthreads();
        sd[t] += x;
        __syncthreads();
    }
    if (t < B) bsum[t] = sd[t] - v;   // exclusive
}

__global__ __launch_bounds__(256) void k_scan3(
    int* __restrict__ a, const int* __restrict__ bsum, int m)
{
    __shared__ int sth[256];
    int t = threadIdx.x;
    int base = blockIdx.x * SCHUNK + t * 4;
    int v[4]; int s = 0;
    #pragma unroll
    for (int i = 0; i < 4; ++i) { int idx = base + i; v[i] = (idx < m) ? a[idx] : 0; s += v[i]; }
    sth[t] = s; __syncthreads();
    int own = s;
    for (int off = 1; off < 256; off <<= 1) {
        int x = (t >= off) ? sth[t - off] : 0;
        __syncthreads();
        sth[t] += x;
        __syncthreads();
    }
    int run = sth[t] - own + bsum[blockIdx.x];
    #pragma unroll
    for (int i = 0; i < 4; ++i) {
        run += v[i];
        int idx = base + i;
        if (idx < m) a[idx] = run;     // inclusive scan overall
    }
}

// atomic-free fill: pos = row_start[d] + rank[e]
__global__ __launch_bounds__(256) void k_fill2(
    const int* __restrict__ srcv, const int* __restrict__ dstv,
    const float* __restrict__ wv, const int* __restrict__ rank,
    const int* __restrict__ row_start, int2* __restrict__ csr, int E)
{
    int e = blockIdx.x * blockDim.x + threadIdx.x;
    int stride = gridDim.x * blockDim.x;
    for (; e < E; e += stride) {
        int d = dstv[e];
        int pos = row_start[d] + rank[e];
        csr[pos] = make_int2(srcv[e], __float_as_int(wv[e]));
    }
}

// ==================== CSR gather (normalized) ====================
__global__ __launch_bounds__(256) void k_gather(
    const float* __restrict__ feat, const int* __restrict__ row_start,
    const int2* __restrict__ csr, const float* __restrict__ deg,
    float* __restrict__ out, int n)
{
    int lane = threadIdx.x & 63;
    int wid  = (int)((blockIdx.x * blockDim.x + threadIdx.x) >> 6);
    int nw   = (int)((gridDim.x * blockDim.x) >> 6);
    for (int v = wid; v < n; v += nw) {
        int beg = row_start[v], end = row_start[v + 1];
        float2 acc = make_float2(0.f, 0.f);
        for (int b = beg; b < end; b += 64) {
            int cnt = end - b; if (cnt > 64) cnt = 64;
            int2 ew = make_int2(0, 0);
            if (lane < cnt) ew = csr[b + lane];
            int sv = ew.x; float wl = __int_as_float(ew.y);
            for (int j = 0; j < cnt; ++j) {
                int   s = __shfl(sv, j);
                float w = __shfl(wl, j);
                float2 f = ((const float2*)(feat + (size_t)s * DIM))[lane];
                acc.x += w * f.x;
                acc.y += w * f.y;
            }
        }
        float dg = deg[v]; dg = dg > 1.f ? dg : 1.f;
        float inv = 1.f / dg;
        ((float2*)(out + (size_t)v * DIM))[lane] = make_float2(acc.x * inv, acc.y * inv);
    }
}

// ==================== fallback atomic scatter ====================
__global__ __launch_bounds__(256) void k_scatter(
    const float* __restrict__ feat,
    const int* __restrict__ srcv, const int* __restrict__ dstv,
    const float* __restrict__ wv,
    float* __restrict__ agg, float* __restrict__ deg, int E, int do_deg)
{
    int lane = threadIdx.x & 63;
    int wid  = (int)((blockIdx.x * blockDim.x + threadIdx.x) >> 6);
    int nw   = (int)((gridDim.x * blockDim.x) >> 6);
    for (int e = wid; e < E; e += nw) {
        int s = srcv[e], d = dstv[e];
        float w = wv[e];
        const float* f = feat + (size_t)s * DIM;
        float* a = agg + (size_t)d * DIM;
        atomicAdd(&a[lane],      w * f[lane]);
        atomicAdd(&a[lane + 64], w * f[lane + 64]);
        if (do_deg && lane == 0) atomicAdd(&deg[d], w);
    }
}

// ==================== dense layers ====================
#define SWS 132
#define SWH 68
#define SW3 68

__global__ __launch_bounds__(256) void k_dense1(
    const float* __restrict__ in, const float* __restrict__ deg,
    const float* __restrict__ W1, const float* __restrict__ b1,
    float* __restrict__ hidden, int n)
{
    __shared__ float sW[DIM * SWH];
    __shared__ float sA[16 * SWS];
    int t = threadIdx.x;
    int row0 = (int)blockIdx.x * 16;

    for (int i = t; i < 16 * DIM; i += 256) {
        int r = i >> 7, k = i & (DIM - 1);
        int row = row0 + r;
        float v = 0.f;
        if (row < n) {
            v = in[(size_t)row * DIM + k];
            if (deg) {
                float dg = deg[row]; dg = dg > 1.f ? dg : 1.f;
                v /= dg;
            }
        }
        sA[r * SWS + k] = v;
    }

    int r  = t >> 4;
    int j0 = t & 15;
    float acc[8];
    #pragma unroll
    for (int jj = 0; jj < 8; ++jj) acc[jj] = b1[j0 + 16 * jj];

    for (int kh = 0; kh < 2; ++kh) {
        __syncthreads();
        for (int i = t; i < DIM * 64; i += 256) {
            int j = i >> 6, k = i & 63;
            sW[j * SWH + k] = W1[j * DIM + kh * 64 + k];
        }
        __syncthreads();
        #pragma unroll 4
        for (int k = 0; k < 64; k += 4) {
            float4 a4 = *(const float4*)&sA[r * SWS + kh * 64 + k];
            #pragma unroll
            for (int jj = 0; jj < 8; ++jj) {
                float4 w4 = *(const float4*)&sW[(j0 + 16 * jj) * SWH + k];
                acc[jj] += a4.x * w4.x + a4.y * w4.y + a4.z * w4.z + a4.w * w4.w;
            }
        }
    }

    int row = row0 + r;
    if (row >= n) return;
    float* h = hidden + (size_t)row * DIM;
    #pragma unroll
    for (int jj = 0; jj < 8; ++jj) {
        float v = acc[jj];
        h[j0 + 16 * jj] = v > 0.f ? v : 0.f;
    }
}

__global__ __launch_bounds__(256) void k_dense2(
    const float* __restrict__ in, const float* __restrict__ deg,
    const float* __restrict__ W2, const float* __restrict__ b2,
    const float* __restrict__ W3, const float* __restrict__ b3,
    float* __restrict__ out_emb, float* __restrict__ out_log, int n)
{
    __shared__ float sW2[DH * SWS];
    __shared__ float sW3[NC * SW3];
    __shared__ float sA[16 * SWS];
    __shared__ float sE[16 * SW3];
    int t = threadIdx.x;
    int row0 = (int)blockIdx.x * 16;

    for (int i = t; i < DH * DIM; i += 256) {
        int j = i >> 7, k = i & (DIM - 1);
        sW2[j * SWS + k] = W2[i];
    }
    for (int i = t; i < NC * DH; i += 256) {
        int c = i / DH, k = i % DH;
        sW3[c * SW3 + k] = W3[i];
    }
    for (int i = t; i < 16 * DIM; i += 256) {
        int r = i >> 7, k = i & (DIM - 1);
        int row = row0 + r;
        float v = 0.f;
        if (row < n) {
            v = in[(size_t)row * DIM + k];
            if (deg) {
                float dg = deg[row]; dg = dg > 1.f ? dg : 1.f;
                v /= dg;
            }
        }
        sA[r * SWS + k] = v;
    }
    __syncthreads();

    {
        int r  = t >> 4;
        int j0 = t & 15;
        int row = row0 + r;
        float acc[4];
        #pragma unroll
        for (int jj = 0; jj < 4; ++jj) acc[jj] = b2[j0 + 16 * jj];
        #pragma unroll 4
        for (int k = 0; k < DIM; k += 4) {
            float4 a4 = *(const float4*)&sA[r * SWS + k];
            #pragma unroll
            for (int jj = 0; jj < 4; ++jj) {
                float4 w4 = *(const float4*)&sW2[(j0 + 16 * jj) * SWS + k];
                acc[jj] += a4.x * w4.x + a4.y * w4.y + a4.z * w4.z + a4.w * w4.w;
            }
        }
        #pragma unroll
        for (int jj = 0; jj < 4; ++jj) {
            sE[r * SW3 + j0 + 16 * jj] = acc[jj];
            if (row < n) out_emb[(size_t)row * DH + j0 + 16 * jj] = acc[jj];
        }
    }
    __syncthreads();

    for (int idx = t; idx < 16 * NC; idx += 256) {
        int r = idx / NC, c = idx % NC;
        int row = row0 + r;
        if (row >= n) continue;
        float acc = b3[c];
        #pragma unroll 8
        for (int k = 0; k < DH; ++k)
            acc += sE[r * SW3 + k] * sW3[c * SW3 + k];
        out_log[(size_t)row * NC + c] = acc;
    }
}

// ==================== launch ====================
extern "C" void kernel_launch(void* const* d_in, const int* in_sizes, int n_in,
                              void* d_out, int out_size, void* d_ws, size_t ws_size,
                              hipStream_t stream)
{
    const float* feat = (const float*)d_in[0];
    const int*   eidx = (const int*)d_in[1];
    const float* ew   = (const float*)d_in[2];
    const float* W1   = (const float*)d_in[3];
    const float* b1   = (const float*)d_in[4];
    const float* W2   = (const float*)d_in[5];
    const float* b2   = (const float*)d_in[6];
    const float* W3   = (const float*)d_in[7];
    const float* b3   = (const float*)d_in[8];

    int E = in_sizes[2];
    int n = in_sizes[0] / DIM;

    const int* srcv = eidx;
    const int* dstv = eidx + E;

    float* out_emb = (float*)d_out;
    float* out_log = out_emb + (size_t)n * DH;

    size_t nf = (size_t)n * DIM;
    float* aggn   = (float*)d_ws;           // nf floats
    float* hidden = aggn + nf;              // nf floats
    float* deg    = hidden + nf;            // n floats
    int*   row_start = (int*)(deg + n);     // n+1 ints
    size_t ofs = 2 * nf + (size_t)n + (size_t)(n + 1);
    ofs = (ofs + 1) & ~(size_t)1;           // 8B-align
    int2*  csr = (int2*)((float*)d_ws + ofs);  // E int2
    size_t need = (ofs + 2 * (size_t)E) * sizeof(float);

    // temporal aliases (dead before aggn/hidden are first written):
    u64* packed = (u64*)aggn;               // n u64, dead after k_extract
    int* bsum   = (int*)(aggn + 2 * (size_t)n); // ~100 ints, dead after k_scan3
    int* rank   = (int*)hidden;             // E ints, dead after k_fill2

    int nblk = (n + 15) / 16;
    int eblk = (E + 255) / 256;

    if (need <= ws_size) {
        // -------- CSR gather path --------
        hipMemsetAsync(packed, 0, (size_t)n * sizeof(u64), stream);
        hipMemsetAsync(row_start, 0, sizeof(int), stream);   // row_start[0] = 0

        k_hist_rank<<<eblk, 256, 0, stream>>>(dstv, ew, packed, rank, E);
        k_extract<<<(n + 255) / 256, 256, 0, stream>>>(packed, row_start, deg, n);

        int m = n + 1;
        int B = (m + SCHUNK - 1) / SCHUNK;
        k_scan1<<<B, 256, 0, stream>>>(row_start, bsum, m);
        k_scan2<<<1, 256, 0, stream>>>(bsum, B);
        k_scan3<<<B, 256, 0, stream>>>(row_start, bsum, m);

        k_fill2<<<eblk, 256, 0, stream>>>(srcv, dstv, ew, rank, row_start, csr, E);

        int gblk = (n + 3) / 4;   // 4 waves/block, 1 wave/node
        k_gather<<<gblk, 256, 0, stream>>>(feat, row_start, csr, deg, aggn, n);
        k_dense1<<<nblk, 256, 0, stream>>>(aggn, nullptr, W1, b1, hidden, n);
        k_gather<<<gblk, 256, 0, stream>>>(hidden, row_start, csr, deg, aggn, n);
        k_dense2<<<nblk, 256, 0, stream>>>(aggn, nullptr, W2, b2, W3, b3, out_emb, out_log, n);
    } else {
        // -------- fallback: atomic scatter path --------
        hipMemsetAsync(aggn, 0, nf * sizeof(float), stream);
        hipMemsetAsync(deg, 0, (size_t)n * sizeof(float), stream);
        k_scatter<<<4096, 256, 0, stream>>>(feat, srcv, dstv, ew, aggn, deg, E, 1);
        k_dense1<<<nblk, 256, 0, stream>>>(aggn, deg, W1, b1, hidden, n);
        hipMemsetAsync(aggn, 0, nf * sizeof(float), stream);
        k_scatter<<<4096, 256, 0, stream>>>(hidden, srcv, dstv, ew, aggn, nullptr, E, 0);
        k_dense2<<<nblk, 256, 0, stream>>>(aggn, deg, W2, b2, W3, b3, out_emb, out_log, n);
    }
}

// Round 4
// 592.804 us; speedup vs baseline: 2.9809x; 1.2277x over previous
//
#include <hip/hip_runtime.h>
#include <cstddef>

#define DIM 128
#define DH 64
#define NC 40
#define SCHUNK 1024
#define DEG_SHIFT 41
#define DEG_SCALE 1048576.0f   // 2^20 fixed-point for deg

typedef unsigned long long u64;

// ==================== CSR build ====================
__global__ __launch_bounds__(256) void k_hist_rank(
    const int* __restrict__ dstv, const float* __restrict__ wv,
    u64* __restrict__ packed, int* __restrict__ rank, int E)
{
    int e = blockIdx.x * blockDim.x + threadIdx.x;
    int stride = gridDim.x * blockDim.x;
    for (; e < E; e += stride) {
        int d = dstv[e];
        unsigned int wfx = (unsigned int)(wv[e] * DEG_SCALE + 0.5f);
        u64 old = atomicAdd(&packed[d], (1ULL << DEG_SHIFT) | (u64)wfx);
        rank[e] = (int)(old >> DEG_SHIFT);
    }
}

__global__ __launch_bounds__(256) void k_extract(
    const u64* __restrict__ packed, int* __restrict__ row_start,
    float* __restrict__ deg, int n)
{
    int v = blockIdx.x * blockDim.x + threadIdx.x;
    if (v >= n) return;
    u64 p = packed[v];
    row_start[v + 1] = (int)(p >> DEG_SHIFT);
    deg[v] = (float)(p & ((1ULL << DEG_SHIFT) - 1)) * (1.0f / DEG_SCALE);
}

__global__ __launch_bounds__(256) void k_scan1(
    const int* __restrict__ a, int* __restrict__ bsum, int m)
{
    __shared__ int sd[256];
    int t = threadIdx.x;
    int base = blockIdx.x * SCHUNK + t * 4;
    int s = 0;
    #pragma unroll
    for (int i = 0; i < 4; ++i) { int idx = base + i; if (idx < m) s += a[idx]; }
    sd[t] = s; __syncthreads();
    for (int off = 128; off > 0; off >>= 1) {
        if (t < off) sd[t] += sd[t + off];
        __syncthreads();
    }
    if (t == 0) bsum[blockIdx.x] = sd[0];
}

__global__ __launch_bounds__(256) void k_scan2(int* __restrict__ bsum, int B)
{
    __shared__ int sd[256];
    int t = threadIdx.x;
    int v = (t < B) ? bsum[t] : 0;
    sd[t] = v; __syncthreads();
    for (int off = 1; off < 256; off <<= 1) {
        int x = (t >= off) ? sd[t - off] : 0;
        __syncthreads();
        sd[t] += x;
        __syncthreads();
    }
    if (t < B) bsum[t] = sd[t] - v;   // exclusive
}

__global__ __launch_bounds__(256) void k_scan3(
    int* __restrict__ a, const int* __restrict__ bsum, int m)
{
    __shared__ int sth[256];
    int t = threadIdx.x;
    int base = blockIdx.x * SCHUNK + t * 4;
    int v[4]; int s = 0;
    #pragma unroll
    for (int i = 0; i < 4; ++i) { int idx = base + i; v[i] = (idx < m) ? a[idx] : 0; s += v[i]; }
    sth[t] = s; __syncthreads();
    int own = s;
    for (int off = 1; off < 256; off <<= 1) {
        int x = (t >= off) ? sth[t - off] : 0;
        __syncthreads();
        sth[t] += x;
        __syncthreads();
    }
    int run = sth[t] - own + bsum[blockIdx.x];
    #pragma unroll
    for (int i = 0; i < 4; ++i) {
        run += v[i];
        int idx = base + i;
        if (idx < m) a[idx] = run;     // inclusive
    }
}

__global__ __launch_bounds__(256) void k_fill2(
    const int* __restrict__ srcv, const int* __restrict__ dstv,
    const float* __restrict__ wv, const int* __restrict__ rank,
    const int* __restrict__ row_start, int2* __restrict__ csr, int E)
{
    int e = blockIdx.x * blockDim.x + threadIdx.x;
    int stride = gridDim.x * blockDim.x;
    for (; e < E; e += stride) {
        int d = dstv[e];
        int pos = row_start[d] + rank[e];
        csr[pos] = make_int2(srcv[e], __float_as_int(wv[e]));
    }
}

// ==================== CSR gather (normalized), float4 lanes ====================
// D/4 lanes per source row; 64/(D/4) rows in flight per wave iteration.
template<int D>
__global__ __launch_bounds__(256) void k_gather_t(
    const float* __restrict__ feat, const int* __restrict__ row_start,
    const int2* __restrict__ csr, const float* __restrict__ deg,
    float* __restrict__ out, int n)
{
    constexpr int G   = D / 4;    // lanes per row
    constexpr int EPW = 64 / G;   // edges per iteration
    int lane = threadIdx.x & 63;
    int sub  = lane / G;          // which edge within group
    int q    = lane % G;          // float4 index within row
    int wid  = (int)((blockIdx.x * blockDim.x + threadIdx.x) >> 6);
    int nw   = (int)((gridDim.x * blockDim.x) >> 6);
    for (int v = wid; v < n; v += nw) {
        int beg = row_start[v], end = row_start[v + 1];
        float4 acc = make_float4(0.f, 0.f, 0.f, 0.f);
        for (int b = beg; b < end; b += 64) {
            int cnt = end - b; if (cnt > 64) cnt = 64;
            int2 ewp = (lane < cnt) ? csr[b + lane] : make_int2(0, 0);
            int sv = ewp.x; float wl = __int_as_float(ewp.y);
            int iters = (cnt + EPW - 1) / EPW;
            for (int j = 0; j < iters; ++j) {
                int   s = __shfl(sv, j * EPW + sub);
                float w = __shfl(wl, j * EPW + sub);
                float4 f = ((const float4*)(feat + (size_t)s * D))[q];
                acc.x += w * f.x; acc.y += w * f.y;
                acc.z += w * f.z; acc.w += w * f.w;
            }
        }
        #pragma unroll
        for (int m = 32; m >= G; m >>= 1) {
            acc.x += __shfl_xor(acc.x, m);
            acc.y += __shfl_xor(acc.y, m);
            acc.z += __shfl_xor(acc.z, m);
            acc.w += __shfl_xor(acc.w, m);
        }
        float dg = deg[v]; dg = dg > 1.f ? dg : 1.f;
        float inv = 1.f / dg;
        if (lane < G)
            ((float4*)(out + (size_t)v * D))[q] =
                make_float4(acc.x * inv, acc.y * inv, acc.z * inv, acc.w * inv);
    }
}

// ==================== fused dense: Z = (relu(agg@W1^T+b1)) @ W2^T ====================
// 32 rows/block; phase1: hidden into LDS (K split in halves); phase2: Z.
__global__ __launch_bounds__(256) void k_dense1z(
    const float* __restrict__ agg, const float* __restrict__ W1,
    const float* __restrict__ b1, const float* __restrict__ W2,
    float* __restrict__ Z, int n)
{
    __shared__ float sA[32 * 132];   // 16896 B
    __shared__ float sW[8704];       // 34816 B: phase1 [128][68], phase2 [64][132]
    __shared__ float sH[32 * 132];   // 16896 B
    int t = threadIdx.x;
    int row0 = (int)blockIdx.x * 32;

    for (int i = t; i < 32 * DIM; i += 256) {
        int r = i >> 7, k = i & (DIM - 1);
        int row = row0 + r;
        sA[r * 132 + k] = (row < n) ? agg[(size_t)row * DIM + k] : 0.f;
    }

    int rg = t >> 4;   // 0..15 -> rows {2rg, 2rg+1}
    int j0 = t & 15;   // cols j0 + 16*jj
    float acc[2][8];
    #pragma unroll
    for (int rr = 0; rr < 2; ++rr)
        #pragma unroll
        for (int jj = 0; jj < 8; ++jj) acc[rr][jj] = b1[j0 + 16 * jj];

    for (int kh = 0; kh < 2; ++kh) {
        __syncthreads();
        for (int i = t; i < DIM * 64; i += 256) {
            int j = i >> 6, k = i & 63;
            sW[j * 68 + k] = W1[j * DIM + kh * 64 + k];
        }
        __syncthreads();
        #pragma unroll 4
        for (int k4 = 0; k4 < 16; ++k4) {
            float4 a4[2];
            #pragma unroll
            for (int rr = 0; rr < 2; ++rr)
                a4[rr] = *(const float4*)&sA[(2 * rg + rr) * 132 + kh * 64 + 4 * k4];
            #pragma unroll
            for (int jj = 0; jj < 8; ++jj) {
                float4 w4 = *(const float4*)&sW[(j0 + 16 * jj) * 68 + 4 * k4];
                #pragma unroll
                for (int rr = 0; rr < 2; ++rr)
                    acc[rr][jj] += a4[rr].x * w4.x + a4[rr].y * w4.y
                                 + a4[rr].z * w4.z + a4[rr].w * w4.w;
            }
        }
    }

    // hidden -> sH (relu)
    #pragma unroll
    for (int rr = 0; rr < 2; ++rr)
        #pragma unroll
        for (int jj = 0; jj < 8; ++jj) {
            float v = acc[rr][jj];
            sH[(2 * rg + rr) * 132 + j0 + 16 * jj] = v > 0.f ? v : 0.f;
        }
    __syncthreads();                     // sH done; safe to overwrite sW
    for (int i = t; i < DH * DIM; i += 256) {
        int j = i >> 7, k = i & (DIM - 1);
        sW[j * 132 + k] = W2[i];
    }
    __syncthreads();

    float acc2[2][4];
    #pragma unroll
    for (int rr = 0; rr < 2; ++rr)
        #pragma unroll
        for (int jj = 0; jj < 4; ++jj) acc2[rr][jj] = 0.f;
    #pragma unroll 4
    for (int k4 = 0; k4 < 32; ++k4) {
        float4 a4[2];
        #pragma unroll
        for (int rr = 0; rr < 2; ++rr)
            a4[rr] = *(const float4*)&sH[(2 * rg + rr) * 132 + 4 * k4];
        #pragma unroll
        for (int jj = 0; jj < 4; ++jj) {
            float4 w4 = *(const float4*)&sW[(j0 + 16 * jj) * 132 + 4 * k4];
            #pragma unroll
            for (int rr = 0; rr < 2; ++rr)
                acc2[rr][jj] += a4[rr].x * w4.x + a4[rr].y * w4.y
                              + a4[rr].z * w4.z + a4[rr].w * w4.w;
        }
    }
    #pragma unroll
    for (int rr = 0; rr < 2; ++rr) {
        int row = row0 + 2 * rg + rr;
        if (row < n)
            #pragma unroll
            for (int jj = 0; jj < 4; ++jj)
                Z[(size_t)row * DH + j0 + 16 * jj] = acc2[rr][jj];
    }
}

// ==================== output: emb = aggz + b2 ; logits = emb@W3^T + b3 ====================
__global__ __launch_bounds__(256) void k_out(
    const float* __restrict__ aggz, const float* __restrict__ b2,
    const float* __restrict__ W3, const float* __restrict__ b3,
    float* __restrict__ out_emb, float* __restrict__ out_log, int n)
{
    __shared__ float sE[16 * 68];
    __shared__ float sW3[NC * 68];
    int t = threadIdx.x;
    int row0 = (int)blockIdx.x * 16;

    for (int i = t; i < NC * DH; i += 256) {
        int c = i >> 6, k = i & 63;
        sW3[c * 68 + k] = W3[i];
    }
    for (int i = t; i < 16 * DH; i += 256) {
        int r = i >> 6, k = i & 63;
        int row = row0 + r;
        float v = 0.f;
        if (row < n) {
            v = aggz[(size_t)row * DH + k] + b2[k];
            out_emb[(size_t)row * DH + k] = v;
        }
        sE[r * 68 + k] = v;
    }
    __syncthreads();

    for (int idx = t; idx < 16 * NC; idx += 256) {
        int r = idx / NC, c = idx % NC;
        int row = row0 + r;
        if (row >= n) continue;
        float acc = b3[c];
        #pragma unroll 8
        for (int k = 0; k < DH; ++k)
            acc += sE[r * 68 + k] * sW3[c * 68 + k];
        out_log[(size_t)row * NC + c] = acc;
    }
}

// ==================== fallback (atomic scatter path, R3-verified) ====================
__global__ __launch_bounds__(256) void k_scatter(
    const float* __restrict__ feat,
    const int* __restrict__ srcv, const int* __restrict__ dstv,
    const float* __restrict__ wv,
    float* __restrict__ agg, float* __restrict__ deg, int E, int do_deg)
{
    int lane = threadIdx.x & 63;
    int wid  = (int)((blockIdx.x * blockDim.x + threadIdx.x) >> 6);
    int nw   = (int)((gridDim.x * blockDim.x) >> 6);
    for (int e = wid; e < E; e += nw) {
        int s = srcv[e], d = dstv[e];
        float w = wv[e];
        const float* f = feat + (size_t)s * DIM;
        float* a = agg + (size_t)d * DIM;
        atomicAdd(&a[lane],      w * f[lane]);
        atomicAdd(&a[lane + 64], w * f[lane + 64]);
        if (do_deg && lane == 0) atomicAdd(&deg[d], w);
    }
}

#define SWS 132
#define SWH 68
#define SW3 68

__global__ __launch_bounds__(256) void k_dense1(
    const float* __restrict__ in, const float* __restrict__ deg,
    const float* __restrict__ W1, const float* __restrict__ b1,
    float* __restrict__ hidden, int n)
{
    __shared__ float sW[DIM * SWH];
    __shared__ float sA[16 * SWS];
    int t = threadIdx.x;
    int row0 = (int)blockIdx.x * 16;

    for (int i = t; i < 16 * DIM; i += 256) {
        int r = i >> 7, k = i & (DIM - 1);
        int row = row0 + r;
        float v = 0.f;
        if (row < n) {
            v = in[(size_t)row * DIM + k];
            if (deg) {
                float dg = deg[row]; dg = dg > 1.f ? dg : 1.f;
                v /= dg;
            }
        }
        sA[r * SWS + k] = v;
    }

    int r  = t >> 4;
    int j0 = t & 15;
    float acc[8];
    #pragma unroll
    for (int jj = 0; jj < 8; ++jj) acc[jj] = b1[j0 + 16 * jj];

    for (int kh = 0; kh < 2; ++kh) {
        __syncthreads();
        for (int i = t; i < DIM * 64; i += 256) {
            int j = i >> 6, k = i & 63;
            sW[j * SWH + k] = W1[j * DIM + kh * 64 + k];
        }
        __syncthreads();
        #pragma unroll 4
        for (int k = 0; k < 64; k += 4) {
            float4 a4 = *(const float4*)&sA[r * SWS + kh * 64 + k];
            #pragma unroll
            for (int jj = 0; jj < 8; ++jj) {
                float4 w4 = *(const float4*)&sW[(j0 + 16 * jj) * SWH + k];
                acc[jj] += a4.x * w4.x + a4.y * w4.y + a4.z * w4.z + a4.w * w4.w;
            }
        }
    }

    int row = row0 + r;
    if (row >= n) return;
    float* h = hidden + (size_t)row * DIM;
    #pragma unroll
    for (int jj = 0; jj < 8; ++jj) {
        float v = acc[jj];
        h[j0 + 16 * jj] = v > 0.f ? v : 0.f;
    }
}

__global__ __launch_bounds__(256) void k_dense2(
    const float* __restrict__ in, const float* __restrict__ deg,
    const float* __restrict__ W2, const float* __restrict__ b2,
    const float* __restrict__ W3, const float* __restrict__ b3,
    float* __restrict__ out_emb, float* __restrict__ out_log, int n)
{
    __shared__ float sW2[DH * SWS];
    __shared__ float sW3f[NC * SW3];
    __shared__ float sA[16 * SWS];
    __shared__ float sE[16 * SW3];
    int t = threadIdx.x;
    int row0 = (int)blockIdx.x * 16;

    for (int i = t; i < DH * DIM; i += 256) {
        int j = i >> 7, k = i & (DIM - 1);
        sW2[j * SWS + k] = W2[i];
    }
    for (int i = t; i < NC * DH; i += 256) {
        int c = i / DH, k = i % DH;
        sW3f[c * SW3 + k] = W3[i];
    }
    for (int i = t; i < 16 * DIM; i += 256) {
        int r = i >> 7, k = i & (DIM - 1);
        int row = row0 + r;
        float v = 0.f;
        if (row < n) {
            v = in[(size_t)row * DIM + k];
            if (deg) {
                float dg = deg[row]; dg = dg > 1.f ? dg : 1.f;
                v /= dg;
            }
        }
        sA[r * SWS + k] = v;
    }
    __syncthreads();

    {
        int r  = t >> 4;
        int j0 = t & 15;
        int row = row0 + r;
        float acc[4];
        #pragma unroll
        for (int jj = 0; jj < 4; ++jj) acc[jj] = b2[j0 + 16 * jj];
        #pragma unroll 4
        for (int k = 0; k < DIM; k += 4) {
            float4 a4 = *(const float4*)&sA[r * SWS + k];
            #pragma unroll
            for (int jj = 0; jj < 4; ++jj) {
                float4 w4 = *(const float4*)&sW2[(j0 + 16 * jj) * SWS + k];
                acc[jj] += a4.x * w4.x + a4.y * w4.y + a4.z * w4.z + a4.w * w4.w;
            }
        }
        #pragma unroll
        for (int jj = 0; jj < 4; ++jj) {
            sE[r * SW3 + j0 + 16 * jj] = acc[jj];
            if (row < n) out_emb[(size_t)row * DH + j0 + 16 * jj] = acc[jj];
        }
    }
    __syncthreads();

    for (int idx = t; idx < 16 * NC; idx += 256) {
        int r = idx / NC, c = idx % NC;
        int row = row0 + r;
        if (row >= n) continue;
        float acc = b3[c];
        #pragma unroll 8
        for (int k = 0; k < DH; ++k)
            acc += sE[r * SW3 + k] * sW3f[c * SW3 + k];
        out_log[(size_t)row * NC + c] = acc;
    }
}

// ==================== launch ====================
extern "C" void kernel_launch(void* const* d_in, const int* in_sizes, int n_in,
                              void* d_out, int out_size, void* d_ws, size_t ws_size,
                              hipStream_t stream)
{
    const float* feat = (const float*)d_in[0];
    const int*   eidx = (const int*)d_in[1];
    const float* ew   = (const float*)d_in[2];
    const float* W1   = (const float*)d_in[3];
    const float* b1   = (const float*)d_in[4];
    const float* W2   = (const float*)d_in[5];
    const float* b2   = (const float*)d_in[6];
    const float* W3   = (const float*)d_in[7];
    const float* b3   = (const float*)d_in[8];

    int E = in_sizes[2];
    int n = in_sizes[0] / DIM;

    const int* srcv = eidx;
    const int* dstv = eidx + E;

    float* out_emb = (float*)d_out;
    float* out_log = out_emb + (size_t)n * DH;

    size_t nf = (size_t)n * DIM;
    size_t nh = (size_t)n * DH;
    float* aggn   = (float*)d_ws;            // nf floats (also: packed u64[n], bsum)
    float* Zbuf   = aggn + nf;               // nh floats (also: rank int[E]; also fallback hidden nf)
    float* aggz   = Zbuf + nf;               // nh floats (nf slot kept for fallback's hidden)
    float* deg    = aggz + nf;               // n floats
    int*   row_start = (int*)(deg + n);      // n+1 ints
    size_t ofs = 3 * nf + (size_t)n + (size_t)(n + 1);
    ofs = (ofs + 1) & ~(size_t)1;            // 8B-align
    int2*  csr = (int2*)((float*)d_ws + ofs); // E int2
    size_t need = (ofs + 2 * (size_t)E) * sizeof(float);

    u64* packed = (u64*)aggn;                    // n u64
    int* bsum   = (int*)(aggn + 2 * (size_t)n);  // ~100 ints
    int* rank   = (int*)Zbuf;                    // E ints, dead after k_fill2

    int nblk16 = (n + 15) / 16;
    int eblk = (E + 255) / 256;

    if (need <= ws_size) {
        // -------- CSR gather path --------
        hipMemsetAsync(packed, 0, (size_t)n * sizeof(u64), stream);
        hipMemsetAsync(row_start, 0, sizeof(int), stream);   // row_start[0] = 0

        k_hist_rank<<<eblk, 256, 0, stream>>>(dstv, ew, packed, rank, E);
        k_extract<<<(n + 255) / 256, 256, 0, stream>>>(packed, row_start, deg, n);

        int m = n + 1;
        int B = (m + SCHUNK - 1) / SCHUNK;
        k_scan1<<<B, 256, 0, stream>>>(row_start, bsum, m);
        k_scan2<<<1, 256, 0, stream>>>(bsum, B);
        k_scan3<<<B, 256, 0, stream>>>(row_start, bsum, m);

        k_fill2<<<eblk, 256, 0, stream>>>(srcv, dstv, ew, rank, row_start, csr, E);

        int gblk = (n + 3) / 4;   // 4 waves/block, 1 wave/node
        k_gather_t<DIM><<<gblk, 256, 0, stream>>>(feat, row_start, csr, deg, aggn, n);
        k_dense1z<<<(n + 31) / 32, 256, 0, stream>>>(aggn, W1, b1, W2, Zbuf, n);
        k_gather_t<DH><<<gblk, 256, 0, stream>>>(Zbuf, row_start, csr, deg, aggz, n);
        k_out<<<nblk16, 256, 0, stream>>>(aggz, b2, W3, b3, out_emb, out_log, n);
    } else {
        // -------- fallback: atomic scatter path (R3) --------
        float* hidden = Zbuf;   // nf floats available
        hipMemsetAsync(aggn, 0, nf * sizeof(float), stream);
        hipMemsetAsync(deg, 0, (size_t)n * sizeof(float), stream);
        k_scatter<<<4096, 256, 0, stream>>>(feat, srcv, dstv, ew, aggn, deg, E, 1);
        k_dense1<<<nblk16, 256, 0, stream>>>(aggn, deg, W1, b1, hidden, n);
        hipMemsetAsync(aggn, 0, nf * sizeof(float), stream);
        k_scatter<<<4096, 256, 0, stream>>>(hidden, srcv, dstv, ew, aggn, nullptr, E, 0);
        k_dense2<<<nblk16, 256, 0, stream>>>(aggn, deg, W2, b2, W3, b3, out_emb, out_log, n);
    }
}

// Round 5
// 410.975 us; speedup vs baseline: 4.2997x; 1.4424x over previous
//
#include <hip/hip_runtime.h>
#include <cstddef>
#include <cstdint>

#define DIM 128
#define DH 64
#define NC 40
#define SCHUNK 1024
#define DEG_SHIFT 41
#define DEG_SCALE 1048576.0f   // 2^20 fixed-point for deg

typedef unsigned long long u64;
typedef short bf16x8 __attribute__((ext_vector_type(8)));
typedef float f32x4  __attribute__((ext_vector_type(4)));

__device__ __forceinline__ unsigned short f2bf(float f) {
    unsigned int u = __float_as_uint(f);
    u += 0x7FFFu + ((u >> 16) & 1u);   // RNE (no NaN inputs here)
    return (unsigned short)(u >> 16);
}
__device__ __forceinline__ float bf2f(unsigned short h) {
    return __uint_as_float(((unsigned int)h) << 16);
}

// ==================== weight / feature bf16 conversion ====================
__global__ __launch_bounds__(256) void k_w2bf(
    const float* __restrict__ W1, const float* __restrict__ W2,
    unsigned short* __restrict__ W1bf, unsigned short* __restrict__ W2bf)
{
    int i = blockIdx.x * 256 + threadIdx.x;
    if (i < DIM * DIM) W1bf[i] = f2bf(W1[i]);
    else if (i < DIM * DIM + DH * DIM) {
        int j = i - DIM * DIM;
        W2bf[j] = f2bf(W2[j]);
    }
}

__global__ __launch_bounds__(256) void k_f2bf(
    const float4* __restrict__ in, ushort4* __restrict__ outp, int n4)
{
    int i = blockIdx.x * blockDim.x + threadIdx.x;
    int stride = gridDim.x * blockDim.x;
    for (; i < n4; i += stride) {
        float4 x = in[i];
        ushort4 o;
        o.x = f2bf(x.x); o.y = f2bf(x.y); o.z = f2bf(x.z); o.w = f2bf(x.w);
        outp[i] = o;
    }
}

// ==================== CSR build ====================
__global__ __launch_bounds__(256) void k_hist_rank(
    const int* __restrict__ dstv, const float* __restrict__ wv,
    u64* __restrict__ packed, int* __restrict__ rank, int E)
{
    int e = blockIdx.x * blockDim.x + threadIdx.x;
    int stride = gridDim.x * blockDim.x;
    for (; e < E; e += stride) {
        int d = dstv[e];
        unsigned int wfx = (unsigned int)(wv[e] * DEG_SCALE + 0.5f);
        u64 old = atomicAdd(&packed[d], (1ULL << DEG_SHIFT) | (u64)wfx);
        rank[e] = (int)(old >> DEG_SHIFT);
    }
}

__global__ __launch_bounds__(256) void k_extract(
    const u64* __restrict__ packed, int* __restrict__ row_start,
    float* __restrict__ deg, int n)
{
    int v = blockIdx.x * blockDim.x + threadIdx.x;
    if (v >= n) return;
    u64 p = packed[v];
    row_start[v + 1] = (int)(p >> DEG_SHIFT);
    deg[v] = (float)(p & ((1ULL << DEG_SHIFT) - 1)) * (1.0f / DEG_SCALE);
}

__global__ __launch_bounds__(256) void k_scan1(
    const int* __restrict__ a, int* __restrict__ bsum, int m)
{
    __shared__ int sd[256];
    int t = threadIdx.x;
    int base = blockIdx.x * SCHUNK + t * 4;
    int s = 0;
    #pragma unroll
    for (int i = 0; i < 4; ++i) { int idx = base + i; if (idx < m) s += a[idx]; }
    sd[t] = s; __syncthreads();
    for (int off = 128; off > 0; off >>= 1) {
        if (t < off) sd[t] += sd[t + off];
        __syncthreads();
    }
    if (t == 0) bsum[blockIdx.x] = sd[0];
}

__global__ __launch_bounds__(256) void k_scan2(int* __restrict__ bsum, int B)
{
    __shared__ int sd[256];
    int t = threadIdx.x;
    int v = (t < B) ? bsum[t] : 0;
    sd[t] = v; __syncthreads();
    for (int off = 1; off < 256; off <<= 1) {
        int x = (t >= off) ? sd[t - off] : 0;
        __syncthreads();
        sd[t] += x;
        __syncthreads();
    }
    if (t < B) bsum[t] = sd[t] - v;   // exclusive
}

__global__ __launch_bounds__(256) void k_scan3(
    int* __restrict__ a, const int* __restrict__ bsum, int m)
{
    __shared__ int sth[256];
    int t = threadIdx.x;
    int base = blockIdx.x * SCHUNK + t * 4;
    int v[4]; int s = 0;
    #pragma unroll
    for (int i = 0; i < 4; ++i) { int idx = base + i; v[i] = (idx < m) ? a[idx] : 0; s += v[i]; }
    sth[t] = s; __syncthreads();
    int own = s;
    for (int off = 1; off < 256; off <<= 1) {
        int x = (t >= off) ? sth[t - off] : 0;
        __syncthreads();
        sth[t] += x;
        __syncthreads();
    }
    int run = sth[t] - own + bsum[blockIdx.x];
    #pragma unroll
    for (int i = 0; i < 4; ++i) {
        run += v[i];
        int idx = base + i;
        if (idx < m) a[idx] = run;     // inclusive
    }
}

__global__ __launch_bounds__(256) void k_fill2(
    const int* __restrict__ srcv, const int* __restrict__ dstv,
    const float* __restrict__ wv, const int* __restrict__ rank,
    const int* __restrict__ row_start, int2* __restrict__ csr, int E)
{
    int e = blockIdx.x * blockDim.x + threadIdx.x;
    int stride = gridDim.x * blockDim.x;
    for (; e < E; e += stride) {
        int d = dstv[e];
        int pos = row_start[d] + rank[e];
        csr[pos] = make_int2(srcv[e], __float_as_int(wv[e]));
    }
}

// ==================== CSR gather from bf16 features, fp32 accum/out ====================
// D/8 lanes per source row (16B each); 64/(D/8) edges in flight per iteration.
template<int D>
__global__ __launch_bounds__(256) void k_gather_bf(
    const unsigned short* __restrict__ feat, const int* __restrict__ row_start,
    const int2* __restrict__ csr, const float* __restrict__ deg,
    float* __restrict__ out, int n)
{
    constexpr int G   = D / 8;    // lanes per row
    constexpr int EPW = 64 / G;   // edges per iteration
    int lane = threadIdx.x & 63;
    int q    = lane & (G - 1);
    int sub  = lane / G;
    int wid  = (int)((blockIdx.x * blockDim.x + threadIdx.x) >> 6);
    int nw   = (int)((gridDim.x * blockDim.x) >> 6);
    for (int v = wid; v < n; v += nw) {
        int beg = row_start[v], end = row_start[v + 1];
        float acc[8];
        #pragma unroll
        for (int e = 0; e < 8; ++e) acc[e] = 0.f;
        for (int b = beg; b < end; b += 64) {
            int cnt = end - b; if (cnt > 64) cnt = 64;
            int2 ewp = (lane < cnt) ? csr[b + lane] : make_int2(0, 0);
            int sv = ewp.x; float wl = __int_as_float(ewp.y);   // wl=0 for pad lanes
            int iters = (cnt + EPW - 1) / EPW;
            for (int j = 0; j < iters; ++j) {
                int ei = j * EPW + sub;
                int   s   = __shfl(sv, ei);
                float wgt = __shfl(wl, ei);
                bf16x8 f = *(const bf16x8*)(feat + (size_t)s * D + q * 8);
                #pragma unroll
                for (int e = 0; e < 8; ++e)
                    acc[e] += wgt * bf2f((unsigned short)f[e]);
            }
        }
        #pragma unroll
        for (int m = 32; m >= G; m >>= 1) {
            #pragma unroll
            for (int e = 0; e < 8; ++e) acc[e] += __shfl_xor(acc[e], m);
        }
        if (lane < G) {
            float dg = deg[v]; dg = dg > 1.f ? dg : 1.f;
            float inv = 1.f / dg;
            float4* dst = (float4*)(out + (size_t)v * D + q * 8);
            dst[0] = make_float4(acc[0]*inv, acc[1]*inv, acc[2]*inv, acc[3]*inv);
            dst[1] = make_float4(acc[4]*inv, acc[5]*inv, acc[6]*inv, acc[7]*inv);
        }
    }
}

// ==================== fused MFMA dense: Z = relu(agg@W1^T+b1) @ W2^T ====================
// 64-row tile/block, 4 waves x 16 rows. All tiles LDS-resident, XOR-swizzled
// (16B block q at row r lives at q^(r&7)) -> conflict-free ds_read_b128.
__global__ __launch_bounds__(256) void k_dense1z(
    const float* __restrict__ agg,
    const unsigned short* __restrict__ W1bf, const float* __restrict__ b1,
    const unsigned short* __restrict__ W2bf,
    unsigned short* __restrict__ Zbf, int n)
{
    __shared__ unsigned short sAgg[64 * 128];   // 16 KB
    __shared__ unsigned short sW1[128 * 128];   // 32 KB
    __shared__ unsigned short sW2[64 * 128];    // 16 KB
    __shared__ unsigned short sHid[64 * 128];   // 16 KB
    int t = threadIdx.x;
    int lane = t & 63;
    int w = t >> 6;
    int row0 = (int)blockIdx.x * 64;

    // stage agg (fp32 -> bf16, swizzled): 1024 16B-blocks
    #pragma unroll
    for (int i = 0; i < 4; ++i) {
        int B = t + 256 * i;
        int r = B >> 4, q = B & 15;
        int row = row0 + r;
        float4 x = make_float4(0.f,0.f,0.f,0.f), y = x;
        if (row < n) {
            const float4* src = (const float4*)(agg + (size_t)row * DIM + q * 8);
            x = src[0]; y = src[1];
        }
        bf16x8 v;
        v[0]=(short)f2bf(x.x); v[1]=(short)f2bf(x.y); v[2]=(short)f2bf(x.z); v[3]=(short)f2bf(x.w);
        v[4]=(short)f2bf(y.x); v[5]=(short)f2bf(y.y); v[6]=(short)f2bf(y.z); v[7]=(short)f2bf(y.w);
        *(bf16x8*)&sAgg[r * 128 + ((q ^ (r & 7)) * 8)] = v;
    }
    // stage W1 (2048 blocks)
    #pragma unroll
    for (int i = 0; i < 8; ++i) {
        int B = t + 256 * i;
        int r = B >> 4, q = B & 15;
        bf16x8 v = *(const bf16x8*)(W1bf + r * 128 + q * 8);
        *(bf16x8*)&sW1[r * 128 + ((q ^ (r & 7)) * 8)] = v;
    }
    // stage W2 (1024 blocks)
    #pragma unroll
    for (int i = 0; i < 4; ++i) {
        int B = t + 256 * i;
        int r = B >> 4, q = B & 15;
        bf16x8 v = *(const bf16x8*)(W2bf + r * 128 + q * 8);
        *(bf16x8*)&sW2[r * 128 + ((q ^ (r & 7)) * 8)] = v;
    }
    __syncthreads();

    int c = lane & 15;        // frag col / A row
    int g = lane >> 4;        // k-group
    int ar = 16 * w + c;      // this wave's A row in tile

    // ---- phase 1: hidden = relu(agg @ W1^T + b1) ----
    bf16x8 a1[4];
    #pragma unroll
    for (int ks = 0; ks < 4; ++ks) {
        int q = ks * 4 + g;
        a1[ks] = *(const bf16x8*)&sAgg[ar * 128 + ((q ^ (ar & 7)) * 8)];
    }
    f32x4 acc[8];
    #pragma unroll
    for (int nt = 0; nt < 8; ++nt) {
        float bv = b1[nt * 16 + c];
        acc[nt] = (f32x4){bv, bv, bv, bv};
    }
    #pragma unroll
    for (int ks = 0; ks < 4; ++ks) {
        #pragma unroll
        for (int nt = 0; nt < 8; ++nt) {
            int rn = nt * 16 + c;
            int q = ks * 4 + g;
            bf16x8 b = *(const bf16x8*)&sW1[rn * 128 + ((q ^ (rn & 7)) * 8)];
            acc[nt] = __builtin_amdgcn_mfma_f32_16x16x32_bf16(a1[ks], b, acc[nt], 0, 0, 0);
        }
    }
    // relu -> sHid (bf16, swizzled). D layout: row=4g+rg, col=nt*16+c
    #pragma unroll
    for (int nt = 0; nt < 8; ++nt) {
        #pragma unroll
        for (int rg = 0; rg < 4; ++rg) {
            float v = acc[nt][rg];
            v = v > 0.f ? v : 0.f;
            int hr = 16 * w + 4 * g + rg;
            int col = nt * 16 + c;
            int qq = col >> 3, oo = col & 7;
            sHid[hr * 128 + ((qq ^ (hr & 7)) * 8) + oo] = f2bf(v);
        }
    }
    __syncthreads();

    // ---- phase 2: Z = hidden @ W2^T ----
    bf16x8 a2[4];
    #pragma unroll
    for (int ks = 0; ks < 4; ++ks) {
        int q = ks * 4 + g;
        a2[ks] = *(const bf16x8*)&sHid[ar * 128 + ((q ^ (ar & 7)) * 8)];
    }
    f32x4 acc2[4];
    #pragma unroll
    for (int nt = 0; nt < 4; ++nt) acc2[nt] = (f32x4){0.f, 0.f, 0.f, 0.f};
    #pragma unroll
    for (int ks = 0; ks < 4; ++ks) {
        #pragma unroll
        for (int nt = 0; nt < 4; ++nt) {
            int rn = nt * 16 + c;
            int q = ks * 4 + g;
            bf16x8 b = *(const bf16x8*)&sW2[rn * 128 + ((q ^ (rn & 7)) * 8)];
            acc2[nt] = __builtin_amdgcn_mfma_f32_16x16x32_bf16(a2[ks], b, acc2[nt], 0, 0, 0);
        }
    }
    #pragma unroll
    for (int nt = 0; nt < 4; ++nt) {
        #pragma unroll
        for (int rg = 0; rg < 4; ++rg) {
            int m = row0 + 16 * w + 4 * g + rg;
            if (m < n) Zbf[(size_t)m * DH + nt * 16 + c] = f2bf(acc2[nt][rg]);
        }
    }
}

// ==================== output: emb = aggz + b2 ; logits = emb@W3^T + b3 ====================
__global__ __launch_bounds__(256) void k_out(
    const float* __restrict__ aggz, const float* __restrict__ b2,
    const float* __restrict__ W3, const float* __restrict__ b3,
    float* __restrict__ out_emb, float* __restrict__ out_log, int n)
{
    __shared__ float sE[16 * 68];
    __shared__ float sW3[NC * 68];
    int t = threadIdx.x;
    int row0 = (int)blockIdx.x * 16;

    for (int i = t; i < NC * DH; i += 256) {
        int cc = i >> 6, k = i & 63;
        sW3[cc * 68 + k] = W3[i];
    }
    for (int i = t; i < 16 * DH; i += 256) {
        int r = i >> 6, k = i & 63;
        int row = row0 + r;
        float v = 0.f;
        if (row < n) {
            v = aggz[(size_t)row * DH + k] + b2[k];
            out_emb[(size_t)row * DH + k] = v;
        }
        sE[r * 68 + k] = v;
    }
    __syncthreads();

    for (int idx = t; idx < 16 * NC; idx += 256) {
        int r = idx / NC, cc = idx % NC;
        int row = row0 + r;
        if (row >= n) continue;
        float acc = b3[cc];
        #pragma unroll 8
        for (int k = 0; k < DH; ++k)
            acc += sE[r * 68 + k] * sW3[cc * 68 + k];
        out_log[(size_t)row * NC + cc] = acc;
    }
}

// ==================== launch ====================
extern "C" void kernel_launch(void* const* d_in, const int* in_sizes, int n_in,
                              void* d_out, int out_size, void* d_ws, size_t ws_size,
                              hipStream_t stream)
{
    const float* feat = (const float*)d_in[0];
    const int*   eidx = (const int*)d_in[1];
    const float* ew   = (const float*)d_in[2];
    const float* W1   = (const float*)d_in[3];
    const float* b1   = (const float*)d_in[4];
    const float* W2   = (const float*)d_in[5];
    const float* b2   = (const float*)d_in[6];
    const float* W3   = (const float*)d_in[7];
    const float* b3   = (const float*)d_in[8];

    int E = in_sizes[2];
    int n = in_sizes[0] / DIM;

    const int* srcv = eidx;
    const int* dstv = eidx + E;

    float* out_emb = (float*)d_out;
    float* out_log = out_emb + (size_t)n * DH;

    size_t nf = (size_t)n * DIM;
    size_t nh = (size_t)n * DH;

    char* wsb = (char*)d_ws;
    size_t off = 0;
    auto alloc = [&](size_t bytes) -> void* {
        void* p = wsb + off;
        off = (off + bytes + 255) & ~(size_t)255;
        return p;
    };
    float*          aggn   = (float*)alloc(nf * 4);                       // fp32 agg
    size_t zbytes = nh * 2 > (size_t)E * 4 ? nh * 2 : (size_t)E * 4;
    unsigned short* Zbf    = (unsigned short*)alloc(zbytes);              // bf16 Z (alias: rank)
    float*          aggz   = (float*)alloc(nh * 4);
    unsigned short* featbf = (unsigned short*)alloc(nf * 2);
    unsigned short* W1bf   = (unsigned short*)alloc((size_t)DIM * DIM * 2);
    unsigned short* W2bf   = (unsigned short*)alloc((size_t)DH * DIM * 2);
    float*          deg    = (float*)alloc((size_t)n * 4);
    int*            row_start = (int*)alloc((size_t)(n + 1) * 4);
    int2*           csr    = (int2*)alloc((size_t)E * 8);

    u64* packed = (u64*)aggn;                     // n u64, dead after k_extract
    int* bsum   = (int*)(aggn + 2 * (size_t)n);   // ~100 ints, dead after scan3
    int* rank   = (int*)Zbf;                      // E ints, dead after k_fill2

    int eblk = (E + 255) / 256;

    // conversions (independent of CSR chain)
    k_w2bf<<<(DIM * DIM + DH * DIM + 255) / 256, 256, 0, stream>>>(W1, W2, W1bf, W2bf);
    int n4 = (int)(nf / 4);
    k_f2bf<<<2048, 256, 0, stream>>>((const float4*)feat, (ushort4*)featbf, n4);

    // CSR build
    hipMemsetAsync(packed, 0, (size_t)n * sizeof(u64), stream);
    hipMemsetAsync(row_start, 0, sizeof(int), stream);   // row_start[0] = 0
    k_hist_rank<<<eblk, 256, 0, stream>>>(dstv, ew, packed, rank, E);
    k_extract<<<(n + 255) / 256, 256, 0, stream>>>(packed, row_start, deg, n);
    int m = n + 1;
    int B = (m + SCHUNK - 1) / SCHUNK;
    k_scan1<<<B, 256, 0, stream>>>(row_start, bsum, m);
    k_scan2<<<1, 256, 0, stream>>>(bsum, B);
    k_scan3<<<B, 256, 0, stream>>>(row_start, bsum, m);
    k_fill2<<<eblk, 256, 0, stream>>>(srcv, dstv, ew, rank, row_start, csr, E);

    // layer 1 aggregate -> fused dense -> layer 2 aggregate -> output
    int gblk = (n + 3) / 4;   // 1 wave/node
    k_gather_bf<DIM><<<gblk, 256, 0, stream>>>(featbf, row_start, csr, deg, aggn, n);
    k_dense1z<<<(n + 63) / 64, 256, 0, stream>>>(aggn, W1bf, b1, W2bf, Zbf, n);
    k_gather_bf<DH><<<gblk, 256, 0, stream>>>(Zbf, row_start, csr, deg, aggz, n);
    k_out<<<(n + 15) / 16, 256, 0, stream>>>(aggz, b2, W3, b3, out_emb, out_log, n);
}

// Round 6
// 381.610 us; speedup vs baseline: 4.6306x; 1.0770x over previous
//
#include <hip/hip_runtime.h>
#include <cstddef>

#define DIM 128
#define DH 64
#define NC 40
#define SCHUNK 1024

typedef unsigned long long u64;
typedef short bf16x8 __attribute__((ext_vector_type(8)));
typedef float f32x4  __attribute__((ext_vector_type(4)));

__device__ __forceinline__ unsigned short f2bf(float f) {
    unsigned int u = __float_as_uint(f);
    u += 0x7FFFu + ((u >> 16) & 1u);   // RNE (no NaNs here)
    return (unsigned short)(u >> 16);
}
__device__ __forceinline__ float bf2f(unsigned short h) {
    return __uint_as_float(((unsigned int)h) << 16);
}

// ==================== fused prep ====================
// blocks [0,HB): hist+rank (4B atomic); [HB,HB+FB): feat->bf16; rest: weights->bf16
__global__ __launch_bounds__(256) void k_prep(
    const int* __restrict__ dstv, int* __restrict__ row_start /*cnt at +1*/,
    int* __restrict__ rank, int E,
    const float4* __restrict__ feat4, ushort4* __restrict__ featbf4, int n8,
    const float* __restrict__ W1, const float* __restrict__ W2,
    unsigned short* __restrict__ W1bf, unsigned short* __restrict__ W2bf,
    int HB, int FB)
{
    int b = blockIdx.x;
    if (b < HB) {
        int e = b * 256 + threadIdx.x;
        if (e < E) {
            int d = dstv[e];
            rank[e] = atomicAdd(&row_start[d + 1], 1);
        }
    } else if (b < HB + FB) {
        int i = (b - HB) * 256 + threadIdx.x;   // 8-float chunk index
        if (i < n8) {
            float4 x = feat4[2 * i], y = feat4[2 * i + 1];
            ushort4 o1, o2;
            o1.x = f2bf(x.x); o1.y = f2bf(x.y); o1.z = f2bf(x.z); o1.w = f2bf(x.w);
            o2.x = f2bf(y.x); o2.y = f2bf(y.y); o2.z = f2bf(y.z); o2.w = f2bf(y.w);
            featbf4[2 * i] = o1; featbf4[2 * i + 1] = o2;
        }
    } else {
        int i = (b - HB - FB) * 256 + threadIdx.x;
        if (i < DIM * DIM) W1bf[i] = f2bf(W1[i]);
        else if (i < DIM * DIM + DH * DIM) {
            int j = i - DIM * DIM;
            W2bf[j] = f2bf(W2[j]);
        }
    }
}

// ==================== scan (inclusive over row_start[0..n]) ====================
__global__ __launch_bounds__(256) void k_scan1(
    const int* __restrict__ a, int* __restrict__ bsum, int m)
{
    __shared__ int sd[256];
    int t = threadIdx.x;
    int base = blockIdx.x * SCHUNK + t * 4;
    int s = 0;
    #pragma unroll
    for (int i = 0; i < 4; ++i) { int idx = base + i; if (idx < m) s += a[idx]; }
    sd[t] = s; __syncthreads();
    for (int off = 128; off > 0; off >>= 1) {
        if (t < off) sd[t] += sd[t + off];
        __syncthreads();
    }
    if (t == 0) bsum[blockIdx.x] = sd[0];
}

__global__ __launch_bounds__(256) void k_scan2(int* __restrict__ bsum, int B)
{
    __shared__ int sd[256];
    int t = threadIdx.x;
    int v = (t < B) ? bsum[t] : 0;
    sd[t] = v; __syncthreads();
    for (int off = 1; off < 256; off <<= 1) {
        int x = (t >= off) ? sd[t - off] : 0;
        __syncthreads();
        sd[t] += x;
        __syncthreads();
    }
    if (t < B) bsum[t] = sd[t] - v;   // exclusive
}

__global__ __launch_bounds__(256) void k_scan3(
    int* __restrict__ a, const int* __restrict__ bsum, int m)
{
    __shared__ int sth[256];
    int t = threadIdx.x;
    int base = blockIdx.x * SCHUNK + t * 4;
    int v[4]; int s = 0;
    #pragma unroll
    for (int i = 0; i < 4; ++i) { int idx = base + i; v[i] = (idx < m) ? a[idx] : 0; s += v[i]; }
    sth[t] = s; __syncthreads();
    int own = s;
    for (int off = 1; off < 256; off <<= 1) {
        int x = (t >= off) ? sth[t - off] : 0;
        __syncthreads();
        sth[t] += x;
        __syncthreads();
    }
    int run = sth[t] - own + bsum[blockIdx.x];
    #pragma unroll
    for (int i = 0; i < 4; ++i) {
        run += v[i];
        int idx = base + i;
        if (idx < m) a[idx] = run;     // inclusive
    }
}

__global__ __launch_bounds__(256) void k_fill2(
    const int* __restrict__ srcv, const int* __restrict__ dstv,
    const float* __restrict__ wv, const int* __restrict__ rank,
    const int* __restrict__ row_start, int2* __restrict__ csr, int E)
{
    int e = blockIdx.x * blockDim.x + threadIdx.x;
    int stride = gridDim.x * blockDim.x;
    for (; e < E; e += stride) {
        int d = dstv[e];
        int pos = row_start[d] + rank[e];
        csr[pos] = make_int2(srcv[e], __float_as_int(wv[e]));
    }
}

// ==================== gather 1: agg = D^-1 A feat; deg computed inline ====================
// 16 lanes per source row (16B each), 4 edges in flight; out bf16 pre-swizzled.
__global__ __launch_bounds__(256) void k_gather1(
    const unsigned short* __restrict__ feat, const int* __restrict__ row_start,
    const int2* __restrict__ csr, float* __restrict__ deg,
    unsigned short* __restrict__ aggbf, int n)
{
    constexpr int G = 16, EPW = 4;
    int lane = threadIdx.x & 63;
    int q    = lane & (G - 1);
    int sub  = lane / G;
    int wid  = (int)((blockIdx.x * blockDim.x + threadIdx.x) >> 6);
    int nw   = (int)((gridDim.x * blockDim.x) >> 6);
    for (int v = wid; v < n; v += nw) {
        int beg = row_start[v], end = row_start[v + 1];
        float acc[8];
        #pragma unroll
        for (int e = 0; e < 8; ++e) acc[e] = 0.f;
        float dsum = 0.f;
        for (int b = beg; b < end; b += 64) {
            int cnt = end - b; if (cnt > 64) cnt = 64;
            int2 ewp = (lane < cnt) ? csr[b + lane] : make_int2(0, 0);
            int sv = ewp.x; float wl = __int_as_float(ewp.y);
            dsum += wl;
            int iters = (cnt + EPW - 1) / EPW;
            for (int j = 0; j < iters; ++j) {
                int ei = j * EPW + sub;
                int   s   = __shfl(sv, ei);
                float wgt = __shfl(wl, ei);
                bf16x8 f = *(const bf16x8*)(feat + (size_t)s * DIM + q * 8);
                #pragma unroll
                for (int e = 0; e < 8; ++e)
                    acc[e] += wgt * bf2f((unsigned short)f[e]);
            }
        }
        #pragma unroll
        for (int m = 32; m >= G; m >>= 1)
            #pragma unroll
            for (int e = 0; e < 8; ++e) acc[e] += __shfl_xor(acc[e], m);
        #pragma unroll
        for (int m = 32; m >= 1; m >>= 1) dsum += __shfl_xor(dsum, m);
        if (lane == 0) deg[v] = dsum;
        float dg = dsum > 1.f ? dsum : 1.f;
        float inv = 1.f / dg;
        if (lane < G) {
            bf16x8 o;
            #pragma unroll
            for (int e = 0; e < 8; ++e) o[e] = (short)f2bf(acc[e] * inv);
            int p = q ^ (v & 7);   // pre-swizzle for dense1z LDS layout
            *(bf16x8*)(aggbf + (size_t)v * DIM + p * 8) = o;
        }
    }
}

// ==================== gather 2: emb = D^-1 A Z + b2 -> d_out ====================
__global__ __launch_bounds__(256) void k_gather2(
    const unsigned short* __restrict__ Zbf, const int* __restrict__ row_start,
    const int2* __restrict__ csr, const float* __restrict__ deg,
    const float* __restrict__ b2, float* __restrict__ out_emb, int n)
{
    constexpr int G = 8, EPW = 8;
    int lane = threadIdx.x & 63;
    int q    = lane & (G - 1);
    int sub  = lane / G;
    int wid  = (int)((blockIdx.x * blockDim.x + threadIdx.x) >> 6);
    int nw   = (int)((gridDim.x * blockDim.x) >> 6);
    for (int v = wid; v < n; v += nw) {
        int beg = row_start[v], end = row_start[v + 1];
        float acc[8];
        #pragma unroll
        for (int e = 0; e < 8; ++e) acc[e] = 0.f;
        for (int b = beg; b < end; b += 64) {
            int cnt = end - b; if (cnt > 64) cnt = 64;
            int2 ewp = (lane < cnt) ? csr[b + lane] : make_int2(0, 0);
            int sv = ewp.x; float wl = __int_as_float(ewp.y);
            int iters = (cnt + EPW - 1) / EPW;
            for (int j = 0; j < iters; ++j) {
                int ei = j * EPW + sub;
                int   s   = __shfl(sv, ei);
                float wgt = __shfl(wl, ei);
                bf16x8 f = *(const bf16x8*)(Zbf + (size_t)s * DH + q * 8);
                #pragma unroll
                for (int e = 0; e < 8; ++e)
                    acc[e] += wgt * bf2f((unsigned short)f[e]);
            }
        }
        #pragma unroll
        for (int m = 32; m >= G; m >>= 1)
            #pragma unroll
            for (int e = 0; e < 8; ++e) acc[e] += __shfl_xor(acc[e], m);
        if (lane < G) {
            float dg = deg[v]; dg = dg > 1.f ? dg : 1.f;
            float inv = 1.f / dg;
            const float4* b2p = (const float4*)(b2 + q * 8);
            float4 ba = b2p[0], bb = b2p[1];
            float4* dst = (float4*)(out_emb + (size_t)v * DH + q * 8);
            dst[0] = make_float4(acc[0]*inv + ba.x, acc[1]*inv + ba.y,
                                 acc[2]*inv + ba.z, acc[3]*inv + ba.w);
            dst[1] = make_float4(acc[4]*inv + bb.x, acc[5]*inv + bb.y,
                                 acc[6]*inv + bb.z, acc[7]*inv + bb.w);
        }
    }
}

// ==================== fused MFMA dense: Z = relu(agg@W1^T+b1) @ W2^T ====================
// 64-row tile, 4 waves x 16 rows; aggbf arrives pre-swizzled (linear copy in).
__global__ __launch_bounds__(256) void k_dense1z(
    const unsigned short* __restrict__ aggbf,
    const unsigned short* __restrict__ W1bf, const float* __restrict__ b1,
    const unsigned short* __restrict__ W2bf,
    unsigned short* __restrict__ Zbf, int n)
{
    __shared__ unsigned short sAgg[64 * 128];   // 16 KB
    __shared__ unsigned short sW1[128 * 128];   // 32 KB
    __shared__ unsigned short sW2[64 * 128];    // 16 KB
    __shared__ unsigned short sHid[64 * 128];   // 16 KB
    int t = threadIdx.x;
    int lane = t & 63;
    int w = t >> 6;
    int row0 = (int)blockIdx.x * 64;

    // stage agg: linear 16B copies (content already swizzled)
    #pragma unroll
    for (int i = 0; i < 4; ++i) {
        int B = t + 256 * i;
        int r = B >> 4, p = B & 15;
        *(bf16x8*)&sAgg[r * 128 + p * 8] =
            *(const bf16x8*)(aggbf + (size_t)(row0 + r) * DIM + p * 8);
    }
    // stage W1 (swizzle at store)
    #pragma unroll
    for (int i = 0; i < 8; ++i) {
        int B = t + 256 * i;
        int r = B >> 4, q = B & 15;
        bf16x8 v = *(const bf16x8*)(W1bf + r * 128 + q * 8);
        *(bf16x8*)&sW1[r * 128 + ((q ^ (r & 7)) * 8)] = v;
    }
    // stage W2
    #pragma unroll
    for (int i = 0; i < 4; ++i) {
        int B = t + 256 * i;
        int r = B >> 4, q = B & 15;
        bf16x8 v = *(const bf16x8*)(W2bf + r * 128 + q * 8);
        *(bf16x8*)&sW2[r * 128 + ((q ^ (r & 7)) * 8)] = v;
    }
    __syncthreads();

    int c = lane & 15;
    int g = lane >> 4;
    int ar = 16 * w + c;

    // phase 1: hidden = relu(agg @ W1^T + b1)
    bf16x8 a1[4];
    #pragma unroll
    for (int ks = 0; ks < 4; ++ks) {
        int q = ks * 4 + g;
        a1[ks] = *(const bf16x8*)&sAgg[ar * 128 + ((q ^ (ar & 7)) * 8)];
    }
    f32x4 acc[8];
    #pragma unroll
    for (int nt = 0; nt < 8; ++nt) {
        float bv = b1[nt * 16 + c];
        acc[nt] = (f32x4){bv, bv, bv, bv};
    }
    #pragma unroll
    for (int ks = 0; ks < 4; ++ks) {
        #pragma unroll
        for (int nt = 0; nt < 8; ++nt) {
            int rn = nt * 16 + c;
            int q = ks * 4 + g;
            bf16x8 b = *(const bf16x8*)&sW1[rn * 128 + ((q ^ (rn & 7)) * 8)];
            acc[nt] = __builtin_amdgcn_mfma_f32_16x16x32_bf16(a1[ks], b, acc[nt], 0, 0, 0);
        }
    }
    #pragma unroll
    for (int nt = 0; nt < 8; ++nt) {
        #pragma unroll
        for (int rg = 0; rg < 4; ++rg) {
            float v = acc[nt][rg];
            v = v > 0.f ? v : 0.f;
            int hr = 16 * w + 4 * g + rg;
            int col = nt * 16 + c;
            int qq = col >> 3, oo = col & 7;
            sHid[hr * 128 + ((qq ^ (hr & 7)) * 8) + oo] = f2bf(v);
        }
    }
    __syncthreads();

    // phase 2: Z = hidden @ W2^T
    bf16x8 a2[4];
    #pragma unroll
    for (int ks = 0; ks < 4; ++ks) {
        int q = ks * 4 + g;
        a2[ks] = *(const bf16x8*)&sHid[ar * 128 + ((q ^ (ar & 7)) * 8)];
    }
    f32x4 acc2[4];
    #pragma unroll
    for (int nt = 0; nt < 4; ++nt) acc2[nt] = (f32x4){0.f, 0.f, 0.f, 0.f};
    #pragma unroll
    for (int ks = 0; ks < 4; ++ks) {
        #pragma unroll
        for (int nt = 0; nt < 4; ++nt) {
            int rn = nt * 16 + c;
            int q = ks * 4 + g;
            bf16x8 b = *(const bf16x8*)&sW2[rn * 128 + ((q ^ (rn & 7)) * 8)];
            acc2[nt] = __builtin_amdgcn_mfma_f32_16x16x32_bf16(a2[ks], b, acc2[nt], 0, 0, 0);
        }
    }
    #pragma unroll
    for (int nt = 0; nt < 4; ++nt) {
        #pragma unroll
        for (int rg = 0; rg < 4; ++rg) {
            int m = row0 + 16 * w + 4 * g + rg;
            if (m < n) Zbf[(size_t)m * DH + nt * 16 + c] = f2bf(acc2[nt][rg]);
        }
    }
}

// ==================== logits = emb @ W3^T + b3 ====================
__global__ __launch_bounds__(256) void k_out(
    const float* __restrict__ emb, const float* __restrict__ W3,
    const float* __restrict__ b3, float* __restrict__ out_log, int n)
{
    __shared__ float sE[16 * 68];
    __shared__ float sW3[NC * 68];
    int t = threadIdx.x;
    int row0 = (int)blockIdx.x * 16;

    for (int i = t; i < NC * DH; i += 256) {
        int cc = i >> 6, k = i & 63;
        sW3[cc * 68 + k] = W3[i];
    }
    for (int i = t; i < 16 * DH; i += 256) {
        int r = i >> 6, k = i & 63;
        int row = row0 + r;
        sE[r * 68 + k] = (row < n) ? emb[(size_t)row * DH + k] : 0.f;
    }
    __syncthreads();

    for (int idx = t; idx < 16 * NC; idx += 256) {
        int r = idx / NC, cc = idx % NC;
        int row = row0 + r;
        if (row >= n) continue;
        float acc = b3[cc];
        #pragma unroll 8
        for (int k = 0; k < DH; ++k)
            acc += sE[r * 68 + k] * sW3[cc * 68 + k];
        out_log[(size_t)row * NC + cc] = acc;
    }
}

// ==================== launch ====================
extern "C" void kernel_launch(void* const* d_in, const int* in_sizes, int n_in,
                              void* d_out, int out_size, void* d_ws, size_t ws_size,
                              hipStream_t stream)
{
    const float* feat = (const float*)d_in[0];
    const int*   eidx = (const int*)d_in[1];
    const float* ew   = (const float*)d_in[2];
    const float* W1   = (const float*)d_in[3];
    const float* b1   = (const float*)d_in[4];
    const float* W2   = (const float*)d_in[5];
    const float* b2   = (const float*)d_in[6];
    const float* W3   = (const float*)d_in[7];
    const float* b3   = (const float*)d_in[8];

    int E = in_sizes[2];
    int n = in_sizes[0] / DIM;
    int npad = (n + 63) & ~63;

    const int* srcv = eidx;
    const int* dstv = eidx + E;

    float* out_emb = (float*)d_out;
    float* out_log = out_emb + (size_t)n * DH;

    size_t nf = (size_t)n * DIM;

    char* wsb = (char*)d_ws;
    size_t off = 0;
    auto alloc = [&](size_t bytes) -> void* {
        void* p = wsb + off;
        off = (off + bytes + 255) & ~(size_t)255;
        return p;
    };
    unsigned short* aggbf  = (unsigned short*)alloc((size_t)npad * DIM * 2); // bf16 agg (alias: bsum)
    size_t zbytes = (size_t)npad * DH * 2;
    if (zbytes < (size_t)E * 4) zbytes = (size_t)E * 4;
    unsigned short* Zbf    = (unsigned short*)alloc(zbytes);                 // bf16 Z (alias: rank)
    unsigned short* featbf = (unsigned short*)alloc(nf * 2);
    unsigned short* W1bf   = (unsigned short*)alloc((size_t)DIM * DIM * 2);
    unsigned short* W2bf   = (unsigned short*)alloc((size_t)DH * DIM * 2);
    float*          deg    = (float*)alloc((size_t)n * 4);
    int*            row_start = (int*)alloc((size_t)(n + 1) * 4);
    int2*           csr    = (int2*)alloc((size_t)E * 8);

    int* rank = (int*)Zbf;     // E ints, dead after k_fill2 (Zbf written later)
    int* bsum = (int*)aggbf;   // ~100 ints, dead after k_scan3 (aggbf written later)

    // counts -> row_start[d+1]; row_start[0] stays 0
    hipMemsetAsync(row_start, 0, (size_t)(n + 1) * sizeof(int), stream);

    int HB = (E + 255) / 256;
    int n8 = (int)(nf / 8);
    int FB = (n8 + 255) / 256;
    int WL = DIM * DIM + DH * DIM;
    int WB = (WL + 255) / 256;
    k_prep<<<HB + FB + WB, 256, 0, stream>>>(
        dstv, row_start, rank, E,
        (const float4*)feat, (ushort4*)featbf, n8,
        W1, W2, W1bf, W2bf, HB, FB);

    int m = n + 1;
    int B = (m + SCHUNK - 1) / SCHUNK;
    k_scan1<<<B, 256, 0, stream>>>(row_start, bsum, m);
    k_scan2<<<1, 256, 0, stream>>>(bsum, B);
    k_scan3<<<B, 256, 0, stream>>>(row_start, bsum, m);

    int eblk = (E + 255) / 256;
    k_fill2<<<eblk, 256, 0, stream>>>(srcv, dstv, ew, rank, row_start, csr, E);

    int gblk = (n + 3) / 4;   // 1 wave/node
    k_gather1<<<gblk, 256, 0, stream>>>(featbf, row_start, csr, deg, aggbf, n);
    k_dense1z<<<npad / 64, 256, 0, stream>>>(aggbf, W1bf, b1, W2bf, Zbf, n);
    k_gather2<<<gblk, 256, 0, stream>>>(Zbf, row_start, csr, deg, b2, out_emb, n);
    k_out<<<(n + 15) / 16, 256, 0, stream>>>(out_emb, W3, b3, out_log, n);
}

// Round 8
// 321.632 us; speedup vs baseline: 5.4941x; 1.1865x over previous
//
#include <hip/hip_runtime.h>
#include <cstddef>

#define DIM 128
#define DH 64
#define NC 40
#define NBLKA 1024
#define BKT 512          // nodes per coarse bucket (dst >> 9)

typedef short bf16x8 __attribute__((ext_vector_type(8)));
typedef float f32x4  __attribute__((ext_vector_type(4)));

__device__ __forceinline__ unsigned short f2bf(float f) {
    unsigned int u = __float_as_uint(f);
    u += 0x7FFFu + ((u >> 16) & 1u);   // RNE (no NaNs here)
    return (unsigned short)(u >> 16);
}
__device__ __forceinline__ float bf2f(unsigned short h) {
    return __uint_as_float(((unsigned int)h) << 16);
}

// ==================== Pass A1: per-block bucket histogram (+ weight conv) ====================
__global__ __launch_bounds__(256) void kA1(
    const int* __restrict__ dstv, int E, int CHUNK,
    int* __restrict__ cnt /* [NBLKA][NBbkt] */, int NBbkt,
    const float* __restrict__ W1, const float* __restrict__ W2,
    unsigned short* __restrict__ W1bf, unsigned short* __restrict__ W2bf)
{
    int b = blockIdx.x;
    if (b < NBLKA) {
        __shared__ int h[256];
        for (int i = threadIdx.x; i < 256; i += 256) h[i] = 0;
        __syncthreads();
        int lo = b * CHUNK, hi = min(E, lo + CHUNK);
        for (int e = lo + threadIdx.x; e < hi; e += 256)
            atomicAdd(&h[dstv[e] >> 9], 1);
        __syncthreads();
        for (int i = threadIdx.x; i < NBbkt; i += 256)
            cnt[(size_t)b * NBbkt + i] = h[i];
    } else {
        int i = (b - NBLKA) * 256 + threadIdx.x;
        if (i < DIM * DIM) W1bf[i] = f2bf(W1[i]);
        else if (i < DIM * DIM + DH * DIM) {
            int j = i - DIM * DIM;
            W2bf[j] = f2bf(W2[j]);
        }
    }
}

// ==================== Pass A2a: per-bucket column scan over blocks ====================
__global__ __launch_bounds__(256) void kA2a(
    int* __restrict__ cnt /* becomes exclOff */, int* __restrict__ total, int NBbkt)
{
    __shared__ int wsum[4];
    int b = blockIdx.x;      // bucket
    int t = threadIdx.x;
    int v[4]; int s = 0;
    #pragma unroll
    for (int i = 0; i < 4; ++i) { v[i] = cnt[(size_t)(4 * t + i) * NBbkt + b]; s += v[i]; }
    int lane = t & 63, wv = t >> 6;
    int si = s;
    #pragma unroll
    for (int off = 1; off < 64; off <<= 1) {
        int x = __shfl_up(si, off);
        if (lane >= off) si += x;
    }
    if (lane == 63) wsum[wv] = si;
    __syncthreads();
    int wbase = 0;
    for (int i = 0; i < wv; ++i) wbase += wsum[i];
    int run = wbase + si - s;
    #pragma unroll
    for (int i = 0; i < 4; ++i) { cnt[(size_t)(4 * t + i) * NBbkt + b] = run; run += v[i]; }
    if (t == 255) total[b] = run;
}

// ==================== Pass A2b: bucket base scan ====================
__global__ __launch_bounds__(256) void kA2b(
    const int* __restrict__ total, int* __restrict__ bucketBase, int NBbkt)
{
    __shared__ int wsum[4];
    int t = threadIdx.x;
    int v = (t < NBbkt) ? total[t] : 0;
    int lane = t & 63, wv = t >> 6;
    int si = v;
    #pragma unroll
    for (int off = 1; off < 64; off <<= 1) {
        int x = __shfl_up(si, off);
        if (lane >= off) si += x;
    }
    if (lane == 63) wsum[wv] = si;
    __syncthreads();
    int wbase = 0;
    for (int i = 0; i < wv; ++i) wbase += wsum[i];
    int incl = wbase + si;
    if (t < NBbkt) bucketBase[t + 1] = incl;
    if (t == 0) bucketBase[0] = 0;
}

// ==================== Pass A3: partition into buckets (+ feat conv) ====================
// staging record: {csrword = (w15<<17)|src17, dstLocal}
__global__ __launch_bounds__(256) void kA3(
    const int* __restrict__ srcv, const int* __restrict__ dstv,
    const float* __restrict__ wv_, int E, int CHUNK,
    const int* __restrict__ exclOff, const int* __restrict__ bucketBase,
    uint2* __restrict__ staging, int NBbkt,
    const float4* __restrict__ feat4, ushort4* __restrict__ featbf4, int n8)
{
    int b = blockIdx.x;
    if (b < NBLKA) {
        __shared__ int cur[256];
        for (int i = threadIdx.x; i < NBbkt; i += 256)
            cur[i] = bucketBase[i] + exclOff[(size_t)b * NBbkt + i];
        __syncthreads();
        int lo = b * CHUNK, hi = min(E, lo + CHUNK);
        for (int e = lo + threadIdx.x; e < hi; e += 256) {
            int d = dstv[e];
            unsigned q = (unsigned)(wv_[e] * 32767.f + 0.5f);
            unsigned word = (q << 17) | (unsigned)srcv[e];
            int pos = atomicAdd(&cur[d >> 9], 1);
            staging[pos] = make_uint2(word, (unsigned)(d & (BKT - 1)));
        }
    } else {
        int i = (b - NBLKA) * 256 + threadIdx.x;   // 8-float chunk
        if (i < n8) {
            float4 x = feat4[2 * i], y = feat4[2 * i + 1];
            ushort4 o1, o2;
            o1.x = f2bf(x.x); o1.y = f2bf(x.y); o1.z = f2bf(x.z); o1.w = f2bf(x.w);
            o2.x = f2bf(y.x); o2.y = f2bf(y.y); o2.z = f2bf(y.z); o2.w = f2bf(y.w);
            featbf4[2 * i] = o1; featbf4[2 * i + 1] = o2;
        }
    }
}

// ==================== Pass B: per-bucket local CSR build ====================
__global__ __launch_bounds__(256) void kB(
    const uint2* __restrict__ staging, const int* __restrict__ bucketBase,
    unsigned* __restrict__ csr, int* __restrict__ row_start, int n)
{
    __shared__ int bins[BKT];
    __shared__ int cur[BKT];
    __shared__ int wsum[4];
    int b = blockIdx.x;
    int base = bucketBase[b], cntE = bucketBase[b + 1] - base;
    int t = threadIdx.x;
    for (int i = t; i < BKT; i += 256) bins[i] = 0;
    __syncthreads();
    for (int i = t; i < cntE; i += 256)
        atomicAdd(&bins[staging[base + i].y], 1);
    __syncthreads();
    int b0 = bins[2 * t], b1 = bins[2 * t + 1];
    int s = b0 + b1;
    int lane = t & 63, wv = t >> 6;
    int si = s;
    #pragma unroll
    for (int off = 1; off < 64; off <<= 1) {
        int x = __shfl_up(si, off);
        if (lane >= off) si += x;
    }
    if (lane == 63) wsum[wv] = si;
    __syncthreads();
    int wbase = 0;
    for (int i = 0; i < wv; ++i) wbase += wsum[i];
    int excl = wbase + si - s;
    int v0 = b * BKT + 2 * t;
    if (v0 <= n)     row_start[v0]     = base + excl;
    if (v0 + 1 <= n) row_start[v0 + 1] = base + excl + b0;
    cur[2 * t]     = base + excl;
    cur[2 * t + 1] = base + excl + b0;
    __syncthreads();
    for (int i = t; i < cntE; i += 256) {
        uint2 r = staging[base + i];
        int pos = atomicAdd(&cur[r.y], 1);
        csr[pos] = r.x;
    }
}

// ==================== gather 1: agg = D^-1 A feat (bf16, pre-swizzled out) ====================
__global__ __launch_bounds__(256) void k_gather1(
    const unsigned short* __restrict__ feat, const int* __restrict__ row_start,
    const unsigned* __restrict__ csr, float* __restrict__ deg,
    unsigned short* __restrict__ aggbf, int n)
{
    constexpr int G = 16, EPW = 4;
    int lane = threadIdx.x & 63;
    int q    = lane & (G - 1);
    int sub  = lane / G;
    int wid  = (int)((blockIdx.x * blockDim.x + threadIdx.x) >> 6);
    int nw   = (int)((gridDim.x * blockDim.x) >> 6);
    for (int v = wid; v < n; v += nw) {
        int beg = row_start[v], end = row_start[v + 1];
        float acc[8];
        #pragma unroll
        for (int e = 0; e < 8; ++e) acc[e] = 0.f;
        float dsum = 0.f;
        for (int b = beg; b < end; b += 64) {
            int cnt = end - b; if (cnt > 64) cnt = 64;
            unsigned word = (lane < cnt) ? csr[b + lane] : 0u;
            dsum += (float)(word >> 17) * (1.f / 32767.f);
            int iters = (cnt + EPW - 1) / EPW;
            for (int j = 0; j < iters; ++j) {
                unsigned wj = (unsigned)__shfl((int)word, j * EPW + sub);
                int   s   = (int)(wj & 0x1FFFFu);
                float wgt = (float)(wj >> 17) * (1.f / 32767.f);
                bf16x8 f = *(const bf16x8*)(feat + (size_t)s * DIM + q * 8);
                #pragma unroll
                for (int e = 0; e < 8; ++e)
                    acc[e] += wgt * bf2f((unsigned short)f[e]);
            }
        }
        #pragma unroll
        for (int m = 32; m >= G; m >>= 1)
            #pragma unroll
            for (int e = 0; e < 8; ++e) acc[e] += __shfl_xor(acc[e], m);
        #pragma unroll
        for (int m = 32; m >= 1; m >>= 1) dsum += __shfl_xor(dsum, m);
        if (lane == 0) deg[v] = dsum;
        float dg = dsum > 1.f ? dsum : 1.f;
        float inv = 1.f / dg;
        if (lane < G) {
            bf16x8 o;
            #pragma unroll
            for (int e = 0; e < 8; ++e) o[e] = (short)f2bf(acc[e] * inv);
            int p = q ^ (v & 7);   // pre-swizzle for dense1z LDS layout
            *(bf16x8*)(aggbf + (size_t)v * DIM + p * 8) = o;
        }
    }
}

// ==================== gather 2: emb = D^-1 A Z + b2 -> d_out ====================
__global__ __launch_bounds__(256) void k_gather2(
    const unsigned short* __restrict__ Zbf, const int* __restrict__ row_start,
    const unsigned* __restrict__ csr, const float* __restrict__ deg,
    const float* __restrict__ b2, float* __restrict__ out_emb, int n)
{
    constexpr int G = 8, EPW = 8;
    int lane = threadIdx.x & 63;
    int q    = lane & (G - 1);
    int sub  = lane / G;
    int wid  = (int)((blockIdx.x * blockDim.x + threadIdx.x) >> 6);
    int nw   = (int)((gridDim.x * blockDim.x) >> 6);
    for (int v = wid; v < n; v += nw) {
        int beg = row_start[v], end = row_start[v + 1];
        float acc[8];
        #pragma unroll
        for (int e = 0; e < 8; ++e) acc[e] = 0.f;
        for (int b = beg; b < end; b += 64) {
            int cnt = end - b; if (cnt > 64) cnt = 64;
            unsigned word = (lane < cnt) ? csr[b + lane] : 0u;
            int iters = (cnt + EPW - 1) / EPW;
            for (int j = 0; j < iters; ++j) {
                unsigned wj = (unsigned)__shfl((int)word, j * EPW + sub);
                int   s   = (int)(wj & 0x1FFFFu);
                float wgt = (float)(wj >> 17) * (1.f / 32767.f);
                bf16x8 f = *(const bf16x8*)(Zbf + (size_t)s * DH + q * 8);
                #pragma unroll
                for (int e = 0; e < 8; ++e)
                    acc[e] += wgt * bf2f((unsigned short)f[e]);
            }
        }
        #pragma unroll
        for (int m = 32; m >= G; m >>= 1)
            #pragma unroll
            for (int e = 0; e < 8; ++e) acc[e] += __shfl_xor(acc[e], m);
        if (lane < G) {
            float dg = deg[v]; dg = dg > 1.f ? dg : 1.f;
            float inv = 1.f / dg;
            const float4* b2p = (const float4*)(b2 + q * 8);
            float4 ba = b2p[0], bb = b2p[1];
            float4* dst = (float4*)(out_emb + (size_t)v * DH + q * 8);
            dst[0] = make_float4(acc[0]*inv + ba.x, acc[1]*inv + ba.y,
                                 acc[2]*inv + ba.z, acc[3]*inv + ba.w);
            dst[1] = make_float4(acc[4]*inv + bb.x, acc[5]*inv + bb.y,
                                 acc[6]*inv + bb.z, acc[7]*inv + bb.w);
        }
    }
}

// ==================== fused MFMA dense: Z = relu(agg@W1^T+b1) @ W2^T ====================
__global__ __launch_bounds__(256) void k_dense1z(
    const unsigned short* __restrict__ aggbf,
    const unsigned short* __restrict__ W1bf, const float* __restrict__ b1,
    const unsigned short* __restrict__ W2bf,
    unsigned short* __restrict__ Zbf, int n)
{
    __shared__ unsigned short sAgg[64 * 128];
    __shared__ unsigned short sW1[128 * 128];
    __shared__ unsigned short sW2[64 * 128];
    __shared__ unsigned short sHid[64 * 128];
    int t = threadIdx.x;
    int lane = t & 63;
    int w = t >> 6;
    int row0 = (int)blockIdx.x * 64;

    #pragma unroll
    for (int i = 0; i < 4; ++i) {
        int B = t + 256 * i;
        int r = B >> 4, p = B & 15;
        *(bf16x8*)&sAgg[r * 128 + p * 8] =
            *(const bf16x8*)(aggbf + (size_t)(row0 + r) * DIM + p * 8);
    }
    #pragma unroll
    for (int i = 0; i < 8; ++i) {
        int B = t + 256 * i;
        int r = B >> 4, q = B & 15;
        bf16x8 v = *(const bf16x8*)(W1bf + r * 128 + q * 8);
        *(bf16x8*)&sW1[r * 128 + ((q ^ (r & 7)) * 8)] = v;
    }
    #pragma unroll
    for (int i = 0; i < 4; ++i) {
        int B = t + 256 * i;
        int r = B >> 4, q = B & 15;
        bf16x8 v = *(const bf16x8*)(W2bf + r * 128 + q * 8);
        *(bf16x8*)&sW2[r * 128 + ((q ^ (r & 7)) * 8)] = v;
    }
    __syncthreads();

    int c = lane & 15;
    int g = lane >> 4;
    int ar = 16 * w + c;

    bf16x8 a1[4];
    #pragma unroll
    for (int ks = 0; ks < 4; ++ks) {
        int q = ks * 4 + g;
        a1[ks] = *(const bf16x8*)&sAgg[ar * 128 + ((q ^ (ar & 7)) * 8)];
    }
    f32x4 acc[8];
    #pragma unroll
    for (int nt = 0; nt < 8; ++nt) {
        float bv = b1[nt * 16 + c];
        acc[nt] = (f32x4){bv, bv, bv, bv};
    }
    #pragma unroll
    for (int ks = 0; ks < 4; ++ks) {
        #pragma unroll
        for (int nt = 0; nt < 8; ++nt) {
            int rn = nt * 16 + c;
            int q = ks * 4 + g;
            bf16x8 b = *(const bf16x8*)&sW1[rn * 128 + ((q ^ (rn & 7)) * 8)];
            acc[nt] = __builtin_amdgcn_mfma_f32_16x16x32_bf16(a1[ks], b, acc[nt], 0, 0, 0);
        }
    }
    #pragma unroll
    for (int nt = 0; nt < 8; ++nt) {
        #pragma unroll
        for (int rg = 0; rg < 4; ++rg) {
            float v = acc[nt][rg];
            v = v > 0.f ? v : 0.f;
            int hr = 16 * w + 4 * g + rg;
            int col = nt * 16 + c;
            int qq = col >> 3, oo = col & 7;
            sHid[hr * 128 + ((qq ^ (hr & 7)) * 8) + oo] = f2bf(v);
        }
    }
    __syncthreads();

    bf16x8 a2[4];
    #pragma unroll
    for (int ks = 0; ks < 4; ++ks) {
        int q = ks * 4 + g;
        a2[ks] = *(const bf16x8*)&sHid[ar * 128 + ((q ^ (ar & 7)) * 8)];
    }
    f32x4 acc2[4];
    #pragma unroll
    for (int nt = 0; nt < 4; ++nt) acc2[nt] = (f32x4){0.f, 0.f, 0.f, 0.f};
    #pragma unroll
    for (int ks = 0; ks < 4; ++ks) {
        #pragma unroll
        for (int nt = 0; nt < 4; ++nt) {
            int rn = nt * 16 + c;
            int q = ks * 4 + g;
            bf16x8 b = *(const bf16x8*)&sW2[rn * 128 + ((q ^ (rn & 7)) * 8)];
            acc2[nt] = __builtin_amdgcn_mfma_f32_16x16x32_bf16(a2[ks], b, acc2[nt], 0, 0, 0);
        }
    }
    #pragma unroll
    for (int nt = 0; nt < 4; ++nt) {
        #pragma unroll
        for (int rg = 0; rg < 4; ++rg) {
            int m = row0 + 16 * w + 4 * g + rg;
            if (m < n) Zbf[(size_t)m * DH + nt * 16 + c] = f2bf(acc2[nt][rg]);
        }
    }
}

// ==================== logits = emb @ W3^T + b3 ====================
__global__ __launch_bounds__(256) void k_out(
    const float* __restrict__ emb, const float* __restrict__ W3,
    const float* __restrict__ b3, float* __restrict__ out_log, int n)
{
    __shared__ float sE[16 * 68];
    __shared__ float sW3[NC * 68];
    int t = threadIdx.x;
    int row0 = (int)blockIdx.x * 16;

    for (int i = t; i < NC * DH; i += 256) {
        int cc = i >> 6, k = i & 63;
        sW3[cc * 68 + k] = W3[i];
    }
    for (int i = t; i < 16 * DH; i += 256) {
        int r = i >> 6, k = i & 63;
        int row = row0 + r;
        sE[r * 68 + k] = (row < n) ? emb[(size_t)row * DH + k] : 0.f;
    }
    __syncthreads();

    for (int idx = t; idx < 16 * NC; idx += 256) {
        int r = idx / NC, cc = idx % NC;
        int row = row0 + r;
        if (row >= n) continue;
        float acc = b3[cc];
        #pragma unroll 8
        for (int k = 0; k < DH; ++k)
            acc += sE[r * 68 + k] * sW3[cc * 68 + k];
        out_log[(size_t)row * NC + cc] = acc;
    }
}

// ==================== launch ====================
extern "C" void kernel_launch(void* const* d_in, const int* in_sizes, int n_in,
                              void* d_out, int out_size, void* d_ws, size_t ws_size,
                              hipStream_t stream)
{
    const float* feat = (const float*)d_in[0];
    const int*   eidx = (const int*)d_in[1];
    const float* ew   = (const float*)d_in[2];
    const float* W1   = (const float*)d_in[3];
    const float* b1   = (const float*)d_in[4];
    const float* W2   = (const float*)d_in[5];
    const float* b2   = (const float*)d_in[6];
    const float* W3   = (const float*)d_in[7];
    const float* b3   = (const float*)d_in[8];

    int E = in_sizes[2];
    int n = in_sizes[0] / DIM;
    int npad = (n + 63) & ~63;
    int NBbkt = (n + BKT - 1) / BKT;     // 196 for n=100000 (<=256 required)
    int CHUNK = (E + NBLKA - 1) / NBLKA;

    const int* srcv = eidx;
    const int* dstv = eidx + E;

    float* out_emb = (float*)d_out;
    float* out_log = out_emb + (size_t)n * DH;

    size_t nf = (size_t)n * DIM;

    char* wsb = (char*)d_ws;
    size_t off = 0;
    auto alloc = [&](size_t bytes) -> void* {
        void* p = wsb + off;
        off = (off + bytes + 255) & ~(size_t)255;
        return p;
    };
    unsigned short* aggbf   = (unsigned short*)alloc((size_t)npad * DIM * 2);
    unsigned short* Zbf     = (unsigned short*)alloc((size_t)npad * DH * 2);
    unsigned short* featbf  = (unsigned short*)alloc(nf * 2);
    unsigned short* W1bf    = (unsigned short*)alloc((size_t)DIM * DIM * 2);
    unsigned short* W2bf    = (unsigned short*)alloc((size_t)DH * DIM * 2);
    float*          deg     = (float*)alloc((size_t)n * 4);
    int*            row_start = (int*)alloc((size_t)(n + 1) * 4);
    unsigned*       csr     = (unsigned*)alloc((size_t)E * 4);
    uint2*          staging = (uint2*)alloc((size_t)E * 8);
    int*            cnt     = (int*)alloc((size_t)NBLKA * NBbkt * 4);
    int*            total   = (int*)alloc((size_t)NBbkt * 4);
    int*            bucketBase = (int*)alloc((size_t)(NBbkt + 1) * 4);

    // A1: bucket histogram per block (+ weight conversion piggyback)
    int WB = (DIM * DIM + DH * DIM + 255) / 256;
    kA1<<<NBLKA + WB, 256, 0, stream>>>(dstv, E, CHUNK, cnt, NBbkt, W1, W2, W1bf, W2bf);
    // A2: offsets
    kA2a<<<NBbkt, 256, 0, stream>>>(cnt, total, NBbkt);
    kA2b<<<1, 256, 0, stream>>>(total, bucketBase, NBbkt);
    // A3: partition (+ feature bf16 conversion piggyback)
    int n8 = (int)(nf / 8);
    int FB = (n8 + 255) / 256;
    kA3<<<NBLKA + FB, 256, 0, stream>>>(srcv, dstv, ew, E, CHUNK, cnt, bucketBase,
                                        staging, NBbkt, (const float4*)feat,
                                        (ushort4*)featbf, n8);
    // B: local CSR build
    kB<<<NBbkt, 256, 0, stream>>>(staging, bucketBase, csr, row_start, n);

    // aggregate -> fused dense -> aggregate -> logits
    int gblk = (n + 3) / 4;
    k_gather1<<<gblk, 256, 0, stream>>>(featbf, row_start, csr, deg, aggbf, n);
    k_dense1z<<<npad / 64, 256, 0, stream>>>(aggbf, W1bf, b1, W2bf, Zbf, n);
    k_gather2<<<gblk, 256, 0, stream>>>(Zbf, row_start, csr, deg, b2, out_emb, n);
    k_out<<<(n + 15) / 16, 256, 0, stream>>>(out_emb, W3, b3, out_log, n);
}